// Round 10
// baseline (278.814 us; speedup 1.0000x reference)
//
#include <hip/hip_runtime.h>
#include <cmath>

// ---------------------------------------------------------------------------
// Types / helpers
// ---------------------------------------------------------------------------
typedef __attribute__((ext_vector_type(8))) short bf16x8;   // 8 bf16 = 4 VGPRs
typedef __attribute__((ext_vector_type(4))) float f32x4;
typedef __attribute__((ext_vector_type(16))) float f32x16;  // 32x32 MFMA acc

__device__ __forceinline__ unsigned short f2b(float f) {   // RNE (cold paths)
    union { float f; unsigned u; } c; c.f = f;
    unsigned r = (c.u + 0x7FFFu + ((c.u >> 16) & 1u)) >> 16;
    return (unsigned short)r;
}
__device__ __forceinline__ unsigned short f2b_hu(float f) { // round-half-up, 2 VALU
    union { float f; unsigned u; } c; c.f = f;
    return (unsigned short)((c.u + 0x8000u) >> 16);
}
__device__ __forceinline__ unsigned pk2(float a, float b) { // pack 2 bf16 (half-up)
    union { float f; unsigned u; } x, y; x.f = a; y.f = b;
    return ((x.u + 0x8000u) >> 16) | (((y.u + 0x8000u) >> 16) << 16);
}
__device__ __forceinline__ float b2f(unsigned short h) {
    union { unsigned u; float f; } c; c.u = ((unsigned)h) << 16;
    return c.f;
}

// async global->LDS 16B (wave-uniform LDS base + lane*16; global src per-lane)
__device__ __forceinline__ void gl2lds16(const unsigned short* g, unsigned short* l) {
    __builtin_amdgcn_global_load_lds(
        (const __attribute__((address_space(1))) unsigned int*)(g),
        (__attribute__((address_space(3))) unsigned int*)(l),
        16, 0, 0);
}

// Problem constants
#define BB   4
#define NN   2048
#define DD   512
#define HH   8
#define DH   64
#define DFF  2048
#define ROWS (BB * NN)          // 8192
#define SCALE_QK 0.044194173824159216f   // 1/sqrt(512)
// 1/sqrt(512) * log2(e): exp(S) == exp2(S') with S' from pre-scaled Q
#define SCALE_QK_E2 0.06376112595042793f

// ---------------------------------------------------------------------------
// LayerNorm row body (fp32 in -> bf16 out), 256 threads per 512-row.
// ---------------------------------------------------------------------------
__device__ __forceinline__ void ln_row_body(const float* __restrict__ X,
                                            const float* __restrict__ g,
                                            const float* __restrict__ be,
                                            unsigned short* __restrict__ out,
                                            int row, int tid, float* sred)
{
    const float* x = X + (size_t)row * DD;
    float x0 = x[tid], x1 = x[tid + 256];
    float s = x0 + x1, sq = x0 * x0 + x1 * x1;
#pragma unroll
    for (int off = 32; off; off >>= 1) {
        s  += __shfl_down(s,  off);
        sq += __shfl_down(sq, off);
    }
    const int wid = tid >> 6;
    if ((tid & 63) == 0) { sred[wid] = s; sred[4 + wid] = sq; }
    __syncthreads();
    float ts = 0.f, tq = 0.f;
#pragma unroll
    for (int i = 0; i < 4; ++i) { ts += sred[i]; tq += sred[4 + i]; }
    const float mean = ts * (1.0f / DD);
    const float var  = tq * (1.0f / DD) - mean * mean;
    const float rinv = rsqrtf(var + 1e-5f);
    unsigned short* o = out + (size_t)row * DD;
    o[tid]       = f2b((x0 - mean) * rinv * g[tid]       + be[tid]);
    o[tid + 256] = f2b((x1 - mean) * rinv * g[tid + 256] + be[tid + 256]);
}

__global__ __launch_bounds__(256)
void ln_kernel(const float* __restrict__ X, const float* __restrict__ g,
               const float* __restrict__ be, unsigned short* __restrict__ out)
{
    __shared__ float sred[8];
    ln_row_body(X, g, be, out, blockIdx.x, threadIdx.x, sred);
}

// ---------------------------------------------------------------------------
// MERGED preprocessing (one launch instead of 4): block-range dispatch.
//   [0, 8192)            : LN(X) -> Xn bf16
//   [8192, 10240)        : cast Y -> Yb bf16 (4 elems/thread)
//   [10240, 13312)       : all weight transposes (3072 32x32 tiles)
//   [13312, 13318)       : bias concat bq|bk|bv -> bqkv
// ---------------------------------------------------------------------------
#define NB_LN   ROWS
#define NB_CAST (ROWS * DD / 4 / 256)
#define NB_TR   3072
#define NB_BIAS 6

__global__ __launch_bounds__(256)
void preprocess_kernel(const float* __restrict__ X, const float* __restrict__ g0,
                       const float* __restrict__ b0, unsigned short* __restrict__ Xn,
                       const float* __restrict__ Y, unsigned short* __restrict__ Yb,
                       const float* __restrict__ Wq, const float* __restrict__ Wk,
                       const float* __restrict__ Wv, const float* __restrict__ Wm,
                       const float* __restrict__ W1, const float* __restrict__ W2,
                       unsigned short* __restrict__ WqkvT, unsigned short* __restrict__ WmT,
                       unsigned short* __restrict__ W1T, unsigned short* __restrict__ W2T,
                       const float* __restrict__ bq, const float* __restrict__ bk,
                       const float* __restrict__ bv, float* __restrict__ bqkv)
{
    __shared__ float smem[32 * 33];
    const int blk = blockIdx.x;
    const int tid = threadIdx.x;

    if (blk < NB_LN) {
        ln_row_body(X, g0, b0, Xn, blk, tid, smem);
    } else if (blk < NB_LN + NB_CAST) {
        int i = (blk - NB_LN) * 256 + tid;
        float4 v = ((const float4*)Y)[i];
        ushort4 o;
        o.x = f2b(v.x); o.y = f2b(v.y); o.z = f2b(v.z); o.w = f2b(v.w);
        ((ushort4*)Yb)[i] = o;
    } else if (blk < NB_LN + NB_CAST + NB_TR) {
        const int t = blk - (NB_LN + NB_CAST);
        float (*tile)[33] = (float(*)[33])smem;
        const float* W; unsigned short* Wt; int K, Nn, n0, k0;
        if (t < 1024) {
            W = W1; Wt = W1T; K = DD; Nn = DFF;
            n0 = (t & 63) * 32; k0 = (t >> 6) * 32;
        } else if (t < 2048) {
            int u = t - 1024;
            W = W2; Wt = W2T; K = DFF; Nn = DD;
            n0 = (u & 15) * 32; k0 = (u >> 4) * 32;
        } else {
            int u = t - 2048;
            int m = u >> 8;            // 0..3 : Wq,Wk,Wv,Wm
            int v = u & 255;
            K = DD; Nn = DD;
            n0 = (v & 15) * 32; k0 = (v >> 4) * 32;
            if (m == 0)      { W = Wq; Wt = WqkvT; }
            else if (m == 1) { W = Wk; Wt = WqkvT + (size_t)DD * DD; }
            else if (m == 2) { W = Wv; Wt = WqkvT + (size_t)2 * DD * DD; }
            else             { W = Wm; Wt = WmT; }
        }
        const int tx = tid & 31, ty = tid >> 5;  // ty 0..7
#pragma unroll
        for (int i = 0; i < 4; ++i)
            tile[ty + i * 8][tx] = W[(size_t)(k0 + ty + i * 8) * Nn + n0 + tx];
        __syncthreads();
#pragma unroll
        for (int i = 0; i < 4; ++i)
            Wt[(size_t)(n0 + ty + i * 8) * K + k0 + tx] = f2b(tile[tx][ty + i * 8]);
    } else {
        int i = (blk - (NB_LN + NB_CAST + NB_TR)) * 256 + tid;   // 0..1535
        float v = (i < 512) ? bq[i] : (i < 1024) ? bk[i - 512] : bv[i - 1024];
        bqkv[i] = v;
    }
}

// ---------------------------------------------------------------------------
// GEMM: C[M,N] = A[M,K] @ Bt[N,K]^T + bias, bf16 in, fp32 accumulate.
// 256 threads (4 waves), double-buffered counted-vmcnt pipeline.
// MT=128: 32x32x16 MFMAs, BK=32, XOR-swizzled [128][32] LDS (both sides).
// MT=64 : 16x16x32 MFMAs, BK=64 (original fragment path).
// NEW (r10): s_setprio(1) around the MFMA clusters -- same T5 mechanism
// that gave attn -6us in r9 (2-4 blocks/CU at uncorrelated phases).
// MODE 1: += bf16 residual (resB), store fp32 (outF)            [mix]
// MODE 2: fast-tanh gelu, store bf16 (outB)                     [FFN1]
// MODE 3: += fp32 residual (resF), store fp32 (outF)            [FFN2]
// MODE 4: fused QKV, N=1536 (MT=128): col<512->Qb, <1024->Kbf, else V
//         transposed into Vtg[b*512+feat][token]; A=(by<4)?A0:A1.
// ---------------------------------------------------------------------------
template <int MODE, int MT>
__global__ __launch_bounds__(256, (MT == 128) ? 4 : 2)
void gemm_bt(const unsigned short* __restrict__ A0, const unsigned short* __restrict__ A1,
             const unsigned short* __restrict__ Bt,
             const float* __restrict__ bias,
             const unsigned short* __restrict__ resB, const float* __restrict__ resF,
             unsigned short* __restrict__ outB, float* __restrict__ outF,
             unsigned short* __restrict__ outQ, unsigned short* __restrict__ outK,
             unsigned short* __restrict__ outVt,
             int M, int N, int K)
{
    const int tid  = threadIdx.x;
    const int wave = tid >> 6, lane = tid & 63;
    const int m0 = blockIdx.x * MT, n0 = blockIdx.y * 128;
    const unsigned short* A = (MODE == 4 && blockIdx.y >= 4) ? A1 : A0;

    if constexpr (MT == 128) {
        // ================= 32x32x16 fragment path =================
        __shared__ __align__(16) unsigned short As[2][128 * 32];
        __shared__ __align__(16) unsigned short Bs[2][128 * 32];
        const int l31 = lane & 31, hi5 = lane >> 5, l3 = lane & 3;
        const int wm = (wave & 1) * 64, wn = (wave >> 1) * 64;

        const int srow4 = lane >> 2;
        const int scsw  = ((lane & 3) ^ (srow4 & 3)) * 8;
        const unsigned short* gA = A  + (size_t)(m0 + wave * 32 + srow4) * K + scsw;
        const unsigned short* gB = Bt + (size_t)(n0 + wave * 32 + srow4) * K + scsw;

        f32x16 acc[2][2];
#pragma unroll
        for (int fi = 0; fi < 2; ++fi)
#pragma unroll
            for (int fj = 0; fj < 2; ++fj)
#pragma unroll
                for (int r = 0; r < 16; ++r) acc[fi][fj][r] = 0.f;

        auto stage = [&](int kk, int buf) {
#pragma unroll
            for (int c = 0; c < 2; ++c) {
                gl2lds16(gA + (size_t)c * 16 * K + kk, &As[buf][(wave * 32 + c * 16) * 32]);
                gl2lds16(gB + (size_t)c * 16 * K + kk, &Bs[buf][(wave * 32 + c * 16) * 32]);
            }
        };
        auto compute = [&](int buf) {
#pragma unroll
            for (int h = 0; h < 2; ++h) {
                const int cs = (((h << 1) + hi5) ^ l3) * 8;   // swizzled chunk
                bf16x8 a[2], b[2];
#pragma unroll
                for (int f = 0; f < 2; ++f) {
                    a[f] = *(const bf16x8*)&As[buf][(wm + f * 32 + l31) * 32 + cs];
                    b[f] = *(const bf16x8*)&Bs[buf][(wn + f * 32 + l31) * 32 + cs];
                }
                __builtin_amdgcn_s_setprio(1);
#pragma unroll
                for (int fi = 0; fi < 2; ++fi)
#pragma unroll
                    for (int fj = 0; fj < 2; ++fj)
                        acc[fi][fj] = __builtin_amdgcn_mfma_f32_32x32x16_bf16(
                            a[fi], b[fj], acc[fi][fj], 0, 0, 0);
                __builtin_amdgcn_s_setprio(0);
            }
        };

        stage(0, 0);
        const int NK = K / 32;
        for (int kt = 0; kt < NK; ++kt) {
            const int cur = kt & 1;
            if (kt + 1 < NK) {
                stage((kt + 1) * 32, cur ^ 1);
                asm volatile("s_waitcnt vmcnt(4)" ::: "memory");
            } else {
                asm volatile("s_waitcnt vmcnt(0)" ::: "memory");
            }
            __builtin_amdgcn_sched_barrier(0);
            __builtin_amdgcn_s_barrier();
            __builtin_amdgcn_sched_barrier(0);
            compute(cur);
            asm volatile("s_waitcnt lgkmcnt(0)" ::: "memory");
            __builtin_amdgcn_sched_barrier(0);
            __builtin_amdgcn_s_barrier();
            __builtin_amdgcn_sched_barrier(0);
        }

        // Epilogue. C/D: col = l31, row = (reg&3) + 8*(reg>>2) + 4*hi5.
#pragma unroll
        for (int fi = 0; fi < 2; ++fi) {
#pragma unroll
            for (int fj = 0; fj < 2; ++fj) {
                const int col = n0 + wn + fj * 32 + l31;
                const float bsv = bias[col];
#pragma unroll
                for (int g = 0; g < 4; ++g) {
                    const int row0 = m0 + wm + fi * 32 + 8 * g + 4 * hi5;
                    if (MODE == 4) {
                        if (col < DD) {
#pragma unroll
                            for (int rr = 0; rr < 4; ++rr)
                                outQ[(size_t)(row0 + rr) * DD + col] =
                                    f2b_hu(acc[fi][fj][4 * g + rr] + bsv);
                        } else if (col < 2 * DD) {
#pragma unroll
                            for (int rr = 0; rr < 4; ++rr)
                                outK[(size_t)(row0 + rr) * DD + (col - DD)] =
                                    f2b_hu(acc[fi][fj][4 * g + rr] + bsv);
                        } else {
                            const int feat = col - 2 * DD;
                            const int bb = row0 >> 11;
                            const int n  = row0 & (NN - 1);
                            ushort4 o;
                            o.x = f2b_hu(acc[fi][fj][4 * g + 0] + bsv);
                            o.y = f2b_hu(acc[fi][fj][4 * g + 1] + bsv);
                            o.z = f2b_hu(acc[fi][fj][4 * g + 2] + bsv);
                            o.w = f2b_hu(acc[fi][fj][4 * g + 3] + bsv);
                            *(ushort4*)&outVt[((size_t)bb * DD + feat) * NN + n] = o;
                        }
                    } else {   // MODE 2: gelu, bf16 store
#pragma unroll
                        for (int rr = 0; rr < 4; ++rr) {
                            float v = acc[fi][fj][4 * g + rr] + bsv;
                            float u = 0.7978845608028654f * (v + 0.044715f * v * v * v);
                            float e = __expf(2.0f * u);
                            float t = 1.0f - 2.0f / (e + 1.0f);
                            outB[(size_t)(row0 + rr) * N + col] = f2b_hu(0.5f * v * (1.0f + t));
                        }
                    }
                }
            }
        }
    } else {
        // ================= 16x16x32 fragment path (MT=64) =================
        __shared__ __align__(16) unsigned short As[2][2][MT * 32];
        __shared__ __align__(16) unsigned short Bs[2][2][128 * 32];
        const int quad = lane >> 4, l16 = lane & 15;
        const int MI  = MT / 32;               // 2 accumulator row-tiles
        const int RPW = MT / 4;                // A rows staged per wave
        const int wm = (wave & 1) * (MT / 2), wn = (wave >> 1) * 64;

        const int srow = lane >> 2;
        const int sc8  = (lane & 3) * 8;
        const unsigned short* gA = A  + (size_t)(m0 + wave * RPW + srow) * K + sc8;
        const unsigned short* gB = Bt + (size_t)(n0 + wave * 32  + srow) * K + sc8;

        f32x4 acc[MI][4];
#pragma unroll
        for (int i = 0; i < MI; ++i)
#pragma unroll
            for (int j = 0; j < 4; ++j)
                acc[i][j] = (f32x4){0.f, 0.f, 0.f, 0.f};

        auto stage = [&](int kk, int buf) {
#pragma unroll
            for (int ih = 0; ih < RPW / 16; ++ih)
#pragma unroll
                for (int half = 0; half < 2; ++half)
                    gl2lds16(gA + (size_t)ih * 16 * K + half * 32 + kk,
                             &As[buf][half][(wave * RPW + ih * 16) * 32]);
#pragma unroll
            for (int ih = 0; ih < 2; ++ih)
#pragma unroll
                for (int half = 0; half < 2; ++half)
                    gl2lds16(gB + (size_t)ih * 16 * K + half * 32 + kk,
                             &Bs[buf][half][(wave * 32 + ih * 16) * 32]);
        };
        auto compute = [&](int buf) {
#pragma unroll
            for (int h = 0; h < 2; ++h) {
                bf16x8 a[MI], b[4];
#pragma unroll
                for (int i = 0; i < MI; ++i)
                    a[i] = *(const bf16x8*)&As[buf][h][(wm + i * 16 + l16) * 32 + quad * 8];
#pragma unroll
                for (int j = 0; j < 4; ++j)
                    b[j] = *(const bf16x8*)&Bs[buf][h][(wn + j * 16 + l16) * 32 + quad * 8];
                __builtin_amdgcn_s_setprio(1);
#pragma unroll
                for (int i = 0; i < MI; ++i)
#pragma unroll
                    for (int j = 0; j < 4; ++j)
                        acc[i][j] = __builtin_amdgcn_mfma_f32_16x16x32_bf16(a[i], b[j], acc[i][j], 0, 0, 0);
                __builtin_amdgcn_s_setprio(0);
            }
        };

        stage(0, 0);
        const int NK = K / 64;
        for (int kt = 0; kt < NK; ++kt) {
            const int cur = kt & 1;
            if (kt + 1 < NK) {
                stage((kt + 1) * 64, cur ^ 1);
                asm volatile("s_waitcnt vmcnt(6)" ::: "memory");
            } else {
                asm volatile("s_waitcnt vmcnt(0)" ::: "memory");
            }
            __builtin_amdgcn_sched_barrier(0);
            __builtin_amdgcn_s_barrier();
            __builtin_amdgcn_sched_barrier(0);
            compute(cur);
            asm volatile("s_waitcnt lgkmcnt(0)" ::: "memory");
            __builtin_amdgcn_sched_barrier(0);
            __builtin_amdgcn_s_barrier();
            __builtin_amdgcn_sched_barrier(0);
        }

        // Epilogue. C/D layout: col = lane&15, row = quad*4 + reg.
#pragma unroll
        for (int i = 0; i < MI; ++i) {
#pragma unroll
            for (int j = 0; j < 4; ++j) {
                const int col  = n0 + wn + j * 16 + l16;
                const int row0 = m0 + wm + i * 16 + quad * 4;
                const float bsv = bias[col];
#pragma unroll
                for (int r = 0; r < 4; ++r) {
                    const size_t idx = (size_t)(row0 + r) * N + col;
                    float v = acc[i][j][r] + bsv;
                    if (MODE == 1) {
                        outF[idx] = v + b2f(resB[idx]);
                    } else {   // MODE 3
                        outF[idx] = v + resF[idx];
                    }
                }
            }
        }
    }
}

// ---------------------------------------------------------------------------
// Flash attention v14 = v13 (56.0us) with ONE barrier per iteration:
// TRIPLE-buffered K/V, staging issued AFTER compute.
//   iter kt: [vmcnt(4) -> barrier -> compute buf[kt%3] -> stage kt+2].
// Race-freedom: buf[k%3] is only overwritten by staging of tile k+3 at
// iter k+1, and a wave reaches that point only after passing barrier k+1,
// which requires ALL waves to have finished compute k.  The v13 second
// barrier (+lgkmcnt drain) is deleted: 32 fewer block barriers, and the
// staging overlaps the barrier wait + other waves' compute (2-deep).
// vmcnt: at top of iter kt, outstanding <= {tile kt, tile kt+1} = 8 calls;
// vmcnt(4) lands tile kt (vmcnt(0) on the last iter).
// Q-hoist moved BEFORE prologue staging so its consumption doesn't drain
// the staging queue.  LDS 66.4KB -> still 2 blocks/CU (grid-capped).
// Keeps: setprio (T5, +6us in r9), XOR-swizzle, XCD swizzle, exp2 fold.
// ---------------------------------------------------------------------------
#define PLD 36   // Pt row stride in dwords (144B, 16B-aligned)

__global__ __launch_bounds__(256, 2)
void flash_attn_kernel(const unsigned short* __restrict__ Q,
                       const unsigned short* __restrict__ Kb,
                       const unsigned short* __restrict__ Vtg,
                       unsigned short* __restrict__ O)
{
    __shared__ __align__(16) unsigned short Ks[3][64 * 64];    // 3 x 8192 B
    __shared__ __align__(16) unsigned short Vt[3][64 * 64];    // 3 x 8192 B
    __shared__ __align__(16) unsigned int   Pt[4 * 32 * PLD];  // 18432 B

    const int tid  = threadIdx.x;
    const int wave = tid >> 6, lane = tid & 63;
    const int quad = lane >> 4, l16 = lane & 15;
    const int lsw  = l16 & 7;              // read-side XOR key (= row&7)

    // XCD swizzle: 512 blocks on 8 XCDs -> XCD x gets work-ids [x*64,(x+1)*64)
    const int bid = (blockIdx.x & 7) * 64 + (blockIdx.x >> 3);
    const int qt = bid & 15;          // 16 q-tiles of 128
    const int bh = bid >> 4;
    const int b  = bh >> 3;
    const int h  = bh & 7;
    const size_t rowbase = (size_t)b * NN * DD;
    const int q0 = qt * 128 + wave * 32;   // this wave's q base (32 q)
    const int hc = h * DH;
    unsigned int* myPt = &Pt[wave * 32 * PLD];

    // staging geometry (unchanged): per tile each wave stages 16 K-rows and
    // 16 V-rows via 2+2 gl2lds16; global source column pre-swizzled ^row.
    const int srow8 = lane >> 3;                       // 0..7
    const int ssw   = ((lane & 7) ^ srow8) * 8;        // elements
    const unsigned short* gKs = Kb  + rowbase + hc;
    const unsigned short* gVs = Vtg + ((size_t)b * DD + hc) * NN;

    // hoist Q B-frags FIRST (their consumption drains vmcnt; do it before
    // any staging is in flight), pre-scaled by log2(e)/sqrt(512)
    bf16x8 Qf[2][2];
#pragma unroll
    for (int t = 0; t < 2; ++t)
#pragma unroll
        for (int hh = 0; hh < 2; ++hh) {
            union { bf16x8 v; unsigned short s[8]; unsigned u[4]; } raw, sc;
            raw.v = *(const bf16x8*)&Q[rowbase + (size_t)(q0 + t * 16 + l16) * DD
                                        + hc + hh * 32 + quad * 8];
#pragma unroll
            for (int p = 0; p < 4; ++p)
                sc.u[p] = pk2(b2f(raw.s[2 * p]) * SCALE_QK_E2, b2f(raw.s[2 * p + 1]) * SCALE_QK_E2);
            Qf[t][hh] = sc.v;
        }

    auto stageKV = [&](int tile, int buf) {
        const int v0 = tile * 64;
#pragma unroll
        for (int c = 0; c < 2; ++c) {
            gl2lds16(gKs + (size_t)(v0 + wave * 16 + c * 8 + srow8) * DD + ssw,
                     &Ks[buf][(wave * 2 + c) * 512]);
            gl2lds16(gVs + (size_t)(wave * 16 + c * 8 + srow8) * NN + v0 + ssw,
                     &Vt[buf][(wave * 2 + c) * 512]);
        }
    };

    // prologue: stage tiles 0 and 1 (8 calls in flight)
    stageKV(0, 0);
    stageKV(1, 1);

    f32x4 Oacc[2][4];   // [q-subtile][dh-tile]: O^T, col=q(l16), row=dh
#pragma unroll
    for (int t = 0; t < 2; ++t)
#pragma unroll
        for (int t2 = 0; t2 < 4; ++t2) Oacc[t][t2] = (f32x4){0.f, 0.f, 0.f, 0.f};
    float lsum[2] = {0.f, 0.f};

    const int NT = NN / 64;
    int cur = 0;   // kt % 3
    for (int kt = 0; kt < NT; ++kt) {
        // wait for tile kt (tile kt+1's 4 calls may stay in flight)
        if (kt + 1 < NT)
            asm volatile("s_waitcnt vmcnt(4)" ::: "memory");
        else
            asm volatile("s_waitcnt vmcnt(0)" ::: "memory");
        __builtin_amdgcn_sched_barrier(0);
        __builtin_amdgcn_s_barrier();
        __builtin_amdgcn_sched_barrier(0);

        // ---- S^T: St[t][j] (16 kv x 16 q); each kf feeds 2 MFMAs ----
        __builtin_amdgcn_s_setprio(1);
        f32x4 St[2][4];
#pragma unroll
        for (int t = 0; t < 2; ++t)
#pragma unroll
            for (int j = 0; j < 4; ++j) St[t][j] = (f32x4){0.f, 0.f, 0.f, 0.f};
#pragma unroll
        for (int j = 0; j < 4; ++j) {
#pragma unroll
            for (int hh = 0; hh < 2; ++hh) {
                bf16x8 kf = *(const bf16x8*)&Ks[cur][(j * 16 + l16) * 64
                                                     + (((hh << 2) + quad) ^ lsw) * 8];
#pragma unroll
                for (int t = 0; t < 2; ++t)
                    St[t][j] = __builtin_amdgcn_mfma_f32_16x16x32_bf16(kf, Qf[t][hh], St[t][j], 0, 0, 0);
            }
        }
        __builtin_amdgcn_s_setprio(0);

        // ---- exp2 (scale+log2e pre-folded into Q), scalar lsum, pack P^T ----
#pragma unroll
        for (int t = 0; t < 2; ++t) {
            unsigned int* rowp = &myPt[(t * 16 + l16) * PLD];
#pragma unroll
            for (int j = 0; j < 4; ++j) {
                float p0 = __builtin_amdgcn_exp2f(St[t][j][0]);
                float p1 = __builtin_amdgcn_exp2f(St[t][j][1]);
                float p2 = __builtin_amdgcn_exp2f(St[t][j][2]);
                float p3 = __builtin_amdgcn_exp2f(St[t][j][3]);
                lsum[t] += (p0 + p1) + (p2 + p3);
                uint2 w; w.x = pk2(p0, p1); w.y = pk2(p2, p3);
                *(uint2*)&rowp[j * 8 + quad * 2] = w;
            }
        }

        // ---- O^T += V^T . P^T : each vf feeds 2 MFMAs ----
        __builtin_amdgcn_s_setprio(1);
#pragma unroll
        for (int ks = 0; ks < 2; ++ks) {
            bf16x8 pf[2];
#pragma unroll
            for (int t = 0; t < 2; ++t)
                pf[t] = *(const bf16x8*)&myPt[(t * 16 + l16) * PLD + ks * 16 + quad * 4];
#pragma unroll
            for (int t2 = 0; t2 < 4; ++t2) {
                bf16x8 vf = *(const bf16x8*)&Vt[cur][(t2 * 16 + l16) * 64
                                                     + (((ks << 2) + quad) ^ lsw) * 8];
#pragma unroll
                for (int t = 0; t < 2; ++t)
                    Oacc[t][t2] = __builtin_amdgcn_mfma_f32_16x16x32_bf16(vf, pf[t], Oacc[t][t2], 0, 0, 0);
            }
        }
        __builtin_amdgcn_s_setprio(0);

        // stage tile kt+2 (safe: buf[(kt+2)%3] was last read at iter kt-1,
        // and every wave passed barrier kt, i.e. finished that read)
        if (kt + 2 < NT)
            stageKV(kt + 2, (cur + 2 >= 3) ? cur - 1 : cur + 2);
        cur = (cur + 1 == 3) ? 0 : cur + 1;
    }

    // reduce lsum across the 4 quads (same q = l16)
#pragma unroll
    for (int t = 0; t < 2; ++t) {
        lsum[t] += __shfl_xor(lsum[t], 16);
        lsum[t] += __shfl_xor(lsum[t], 32);
    }
    const float rl0 = 1.0f / lsum[0], rl1 = 1.0f / lsum[1];

    // transpose O^T -> O via wave-private LDS (reuse Pt), coalesced store
#pragma unroll
    for (int t = 0; t < 2; ++t) {
        const float rl = t ? rl1 : rl0;
        unsigned int* rowp = &myPt[(t * 16 + l16) * PLD];
#pragma unroll
        for (int t2 = 0; t2 < 4; ++t2) {
            uint2 w;
            w.x = pk2(Oacc[t][t2][0] * rl, Oacc[t][t2][1] * rl);
            w.y = pk2(Oacc[t][t2][2] * rl, Oacc[t][t2][3] * rl);
            *(uint2*)&rowp[t2 * 8 + quad * 2] = w;
        }
    }
#pragma unroll
    for (int ii = 0; ii < 4; ++ii) {
        int flat  = lane + ii * 64;       // 0..255 within wave
        int row   = flat >> 3;            // q within wave (0..31)
        int chunk = flat & 7;
        uint4 v = *(const uint4*)&myPt[row * PLD + chunk * 4];
        *(uint4*)&O[rowbase + (size_t)(q0 + row) * DD + hc + chunk * 8] = v;
    }
}

// ---------------------------------------------------------------------------
// Launch
// ---------------------------------------------------------------------------
extern "C" void kernel_launch(void* const* d_in, const int* in_sizes, int n_in,
                              void* d_out, int out_size, void* d_ws, size_t ws_size,
                              hipStream_t stream)
{
    (void)in_sizes; (void)n_in; (void)out_size; (void)ws_size;

    const float* X   = (const float*)d_in[0];
    const float* Y   = (const float*)d_in[1];
    const float* Wq  = (const float*)d_in[2];
    const float* bq  = (const float*)d_in[3];
    const float* Wk  = (const float*)d_in[4];
    const float* bk  = (const float*)d_in[5];
    const float* Wv  = (const float*)d_in[6];
    const float* bv  = (const float*)d_in[7];
    const float* Wm  = (const float*)d_in[8];
    const float* bm  = (const float*)d_in[9];
    const float* g0  = (const float*)d_in[10];
    const float* b0  = (const float*)d_in[11];
    const float* g1  = (const float*)d_in[12];
    const float* b1  = (const float*)d_in[13];
    const float* W1  = (const float*)d_in[14];
    const float* bb1 = (const float*)d_in[15];
    const float* W2  = (const float*)d_in[16];
    const float* bb2 = (const float*)d_in[17];
    float* out = (float*)d_out;

    // workspace carve-up
    char* ws = (char*)d_ws;
    size_t off = 0;
    auto carve = [&](size_t bytes) { void* p = ws + off; off += bytes; return p; };
    const size_t BND2 = (size_t)ROWS * DD * 2;       // 8 MB bf16 [8192,512]

    unsigned short* Xn   = (unsigned short*)carve(BND2);
    unsigned short* Yb   = (unsigned short*)carve(BND2);
    unsigned short* WqkvT= (unsigned short*)carve((size_t)3 * DD * DD * 2);
    unsigned short* WmT  = (unsigned short*)carve((size_t)DD * DD * 2);
    unsigned short* W1T  = (unsigned short*)carve((size_t)DD * DFF * 2);
    unsigned short* W2T  = (unsigned short*)carve((size_t)DFF * DD * 2);
    float*          bqkv = (float*)carve(1536 * 4);
    unsigned short* Qb   = (unsigned short*)carve(BND2);
    unsigned short* Kbf  = (unsigned short*)carve(BND2);
    unsigned short* Vtg  = (unsigned short*)carve(BND2);  // V^T [b*512+feat][token]
    float*          Hx   = (float*)carve((size_t)ROWS * DD * 4);
    unsigned short* G    = (unsigned short*)carve((size_t)ROWS * DFF * 2);
    unsigned short* Mh   = Xn;   // reuse: Xn dead after QKV
    unsigned short* Hn   = Yb;   // reuse: Yb dead after QKV

    // 1+2. merged preprocessing: LN(X), cast(Y), all transposes, bias concat
    preprocess_kernel<<<NB_LN + NB_CAST + NB_TR + NB_BIAS, 256, 0, stream>>>(
        X, g0, b0, Xn, Y, Yb,
        Wq, Wk, Wv, Wm, W1, W2, WqkvT, WmT, W1T, W2T,
        bq, bk, bv, bqkv);

    // 3. fused QKV projection (768 blocks, 3/CU; 32x32 frags, dbuf BK=32)
    gemm_bt<4, 128><<<dim3(ROWS / 128, 12), 256, 0, stream>>>(
        Xn, Yb, WqkvT, bqkv, nullptr, nullptr, nullptr, nullptr,
        Qb, Kbf, Vtg, ROWS, 3 * DD, DD);

    // 4. attention (512 blocks of 256 threads: b,h,16 q-tiles of 128)
    flash_attn_kernel<<<BB * HH * (NN / 128), 256, 0, stream>>>(Qb, Kbf, Vtg, Mh);

    // 5. head mix + residual (Q) -> Hx fp32   (MT=64 dbuf -> 512 blocks, 2/CU)
    gemm_bt<1, 64><<<dim3(ROWS / 64, DD / 128), 256, 0, stream>>>(
        Mh, nullptr, WmT, bm, Qb, nullptr, nullptr, Hx,
        nullptr, nullptr, nullptr, ROWS, DD, DD);

    // 6. LN(Hx) -> Hn bf16
    ln_kernel<<<ROWS, 256, 0, stream>>>(Hx, g1, b1, Hn);

    // 7. FFN1 + fast gelu -> G bf16  (1024 blocks, 4/CU; 32x32 frags, BK=32)
    gemm_bt<2, 128><<<dim3(ROWS / 128, DFF / 128), 256, 0, stream>>>(
        Hn, nullptr, W1T, bb1, nullptr, nullptr, G, nullptr,
        nullptr, nullptr, nullptr, ROWS, DFF, DD);

    // 8. FFN2 + residual (Hx) -> out fp32  (MT=64 dbuf -> 512 blocks, 2/CU)
    gemm_bt<3, 64><<<dim3(ROWS / 64, DD / 128), 256, 0, stream>>>(
        G, nullptr, W2T, bb2, nullptr, Hx, nullptr, out,
        nullptr, nullptr, nullptr, ROWS, DD, DFF);
}

// Round 11
// 275.758 us; speedup vs baseline: 1.0111x; 1.0111x over previous
//
#include <hip/hip_runtime.h>
#include <cmath>

// ---------------------------------------------------------------------------
// Types / helpers
// ---------------------------------------------------------------------------
typedef __attribute__((ext_vector_type(8))) short bf16x8;   // 8 bf16 = 4 VGPRs
typedef __attribute__((ext_vector_type(4))) float f32x4;
typedef __attribute__((ext_vector_type(16))) float f32x16;  // 32x32 MFMA acc

__device__ __forceinline__ unsigned short f2b(float f) {   // RNE (cold paths)
    union { float f; unsigned u; } c; c.f = f;
    unsigned r = (c.u + 0x7FFFu + ((c.u >> 16) & 1u)) >> 16;
    return (unsigned short)r;
}
__device__ __forceinline__ unsigned short f2b_hu(float f) { // round-half-up, 2 VALU
    union { float f; unsigned u; } c; c.f = f;
    return (unsigned short)((c.u + 0x8000u) >> 16);
}
__device__ __forceinline__ unsigned pk2(float a, float b) { // pack 2 bf16 (half-up)
    union { float f; unsigned u; } x, y; x.f = a; y.f = b;
    return ((x.u + 0x8000u) >> 16) | (((y.u + 0x8000u) >> 16) << 16);
}
__device__ __forceinline__ float b2f(unsigned short h) {
    union { unsigned u; float f; } c; c.u = ((unsigned)h) << 16;
    return c.f;
}

// async global->LDS 16B (wave-uniform LDS base + lane*16; global src per-lane)
__device__ __forceinline__ void gl2lds16(const unsigned short* g, unsigned short* l) {
    __builtin_amdgcn_global_load_lds(
        (const __attribute__((address_space(1))) unsigned int*)(g),
        (__attribute__((address_space(3))) unsigned int*)(l),
        16, 0, 0);
}

// Problem constants
#define BB   4
#define NN   2048
#define DD   512
#define HH   8
#define DH   64
#define DFF  2048
#define ROWS (BB * NN)          // 8192
#define SCALE_QK 0.044194173824159216f   // 1/sqrt(512)
// 1/sqrt(512) * log2(e): exp(S) == exp2(S') with S' from pre-scaled Q
#define SCALE_QK_E2 0.06376112595042793f

// ---------------------------------------------------------------------------
// LayerNorm row body (fp32 in -> bf16 out), 256 threads per 512-row.
// ---------------------------------------------------------------------------
__device__ __forceinline__ void ln_row_body(const float* __restrict__ X,
                                            const float* __restrict__ g,
                                            const float* __restrict__ be,
                                            unsigned short* __restrict__ out,
                                            int row, int tid, float* sred)
{
    const float* x = X + (size_t)row * DD;
    float x0 = x[tid], x1 = x[tid + 256];
    float s = x0 + x1, sq = x0 * x0 + x1 * x1;
#pragma unroll
    for (int off = 32; off; off >>= 1) {
        s  += __shfl_down(s,  off);
        sq += __shfl_down(sq, off);
    }
    const int wid = tid >> 6;
    if ((tid & 63) == 0) { sred[wid] = s; sred[4 + wid] = sq; }
    __syncthreads();
    float ts = 0.f, tq = 0.f;
#pragma unroll
    for (int i = 0; i < 4; ++i) { ts += sred[i]; tq += sred[4 + i]; }
    const float mean = ts * (1.0f / DD);
    const float var  = tq * (1.0f / DD) - mean * mean;
    const float rinv = rsqrtf(var + 1e-5f);
    unsigned short* o = out + (size_t)row * DD;
    o[tid]       = f2b((x0 - mean) * rinv * g[tid]       + be[tid]);
    o[tid + 256] = f2b((x1 - mean) * rinv * g[tid + 256] + be[tid + 256]);
}

__global__ __launch_bounds__(256)
void ln_kernel(const float* __restrict__ X, const float* __restrict__ g,
               const float* __restrict__ be, unsigned short* __restrict__ out)
{
    __shared__ float sred[8];
    ln_row_body(X, g, be, out, blockIdx.x, threadIdx.x, sred);
}

// ---------------------------------------------------------------------------
// MERGED preprocessing (one launch instead of 4): block-range dispatch.
//   [0, 8192)            : LN(X) -> Xn bf16
//   [8192, 10240)        : cast Y -> Yb bf16 (4 elems/thread)
//   [10240, 13312)       : all weight transposes (3072 32x32 tiles)
//   [13312, 13318)       : bias concat bq|bk|bv -> bqkv
// ---------------------------------------------------------------------------
#define NB_LN   ROWS
#define NB_CAST (ROWS * DD / 4 / 256)
#define NB_TR   3072
#define NB_BIAS 6

__global__ __launch_bounds__(256)
void preprocess_kernel(const float* __restrict__ X, const float* __restrict__ g0,
                       const float* __restrict__ b0, unsigned short* __restrict__ Xn,
                       const float* __restrict__ Y, unsigned short* __restrict__ Yb,
                       const float* __restrict__ Wq, const float* __restrict__ Wk,
                       const float* __restrict__ Wv, const float* __restrict__ Wm,
                       const float* __restrict__ W1, const float* __restrict__ W2,
                       unsigned short* __restrict__ WqkvT, unsigned short* __restrict__ WmT,
                       unsigned short* __restrict__ W1T, unsigned short* __restrict__ W2T,
                       const float* __restrict__ bq, const float* __restrict__ bk,
                       const float* __restrict__ bv, float* __restrict__ bqkv)
{
    __shared__ float smem[32 * 33];
    const int blk = blockIdx.x;
    const int tid = threadIdx.x;

    if (blk < NB_LN) {
        ln_row_body(X, g0, b0, Xn, blk, tid, smem);
    } else if (blk < NB_LN + NB_CAST) {
        int i = (blk - NB_LN) * 256 + tid;
        float4 v = ((const float4*)Y)[i];
        ushort4 o;
        o.x = f2b(v.x); o.y = f2b(v.y); o.z = f2b(v.z); o.w = f2b(v.w);
        ((ushort4*)Yb)[i] = o;
    } else if (blk < NB_LN + NB_CAST + NB_TR) {
        const int t = blk - (NB_LN + NB_CAST);
        float (*tile)[33] = (float(*)[33])smem;
        const float* W; unsigned short* Wt; int K, Nn, n0, k0;
        if (t < 1024) {
            W = W1; Wt = W1T; K = DD; Nn = DFF;
            n0 = (t & 63) * 32; k0 = (t >> 6) * 32;
        } else if (t < 2048) {
            int u = t - 1024;
            W = W2; Wt = W2T; K = DFF; Nn = DD;
            n0 = (u & 15) * 32; k0 = (u >> 4) * 32;
        } else {
            int u = t - 2048;
            int m = u >> 8;            // 0..3 : Wq,Wk,Wv,Wm
            int v = u & 255;
            K = DD; Nn = DD;
            n0 = (v & 15) * 32; k0 = (v >> 4) * 32;
            if (m == 0)      { W = Wq; Wt = WqkvT; }
            else if (m == 1) { W = Wk; Wt = WqkvT + (size_t)DD * DD; }
            else if (m == 2) { W = Wv; Wt = WqkvT + (size_t)2 * DD * DD; }
            else             { W = Wm; Wt = WmT; }
        }
        const int tx = tid & 31, ty = tid >> 5;  // ty 0..7
#pragma unroll
        for (int i = 0; i < 4; ++i)
            tile[ty + i * 8][tx] = W[(size_t)(k0 + ty + i * 8) * Nn + n0 + tx];
        __syncthreads();
#pragma unroll
        for (int i = 0; i < 4; ++i)
            Wt[(size_t)(n0 + ty + i * 8) * K + k0 + tx] = f2b(tile[tx][ty + i * 8]);
    } else {
        int i = (blk - (NB_LN + NB_CAST + NB_TR)) * 256 + tid;   // 0..1535
        float v = (i < 512) ? bq[i] : (i < 1024) ? bk[i - 512] : bv[i - 1024];
        bqkv[i] = v;
    }
}

// ---------------------------------------------------------------------------
// GEMM: C[M,N] = A[M,K] @ Bt[N,K]^T + bias, bf16 in, fp32 accumulate.
// 256 threads (4 waves), double-buffered counted-vmcnt pipeline, with
// s_setprio(1) around the MFMA clusters (T5; isolated -2.2us in r10).
// MT=128: 32x32x16 MFMAs, BK=32, XOR-swizzled [128][32] LDS (both sides).
// MT=64 : 16x16x32 MFMAs, BK=64 (original fragment path).
// MODE 1: += bf16 residual (resB), store fp32 (outF)            [mix]
// MODE 2: fast-tanh gelu, store bf16 (outB)                     [FFN1]
// MODE 3: += fp32 residual (resF), store fp32 (outF)            [FFN2]
// MODE 4: fused QKV, N=1536 (MT=128): col<512->Qb, <1024->Kbf, else V
//         transposed into Vtg[b*512+feat][token]; A=(by<4)?A0:A1.
// ---------------------------------------------------------------------------
template <int MODE, int MT>
__global__ __launch_bounds__(256, (MT == 128) ? 4 : 2)
void gemm_bt(const unsigned short* __restrict__ A0, const unsigned short* __restrict__ A1,
             const unsigned short* __restrict__ Bt,
             const float* __restrict__ bias,
             const unsigned short* __restrict__ resB, const float* __restrict__ resF,
             unsigned short* __restrict__ outB, float* __restrict__ outF,
             unsigned short* __restrict__ outQ, unsigned short* __restrict__ outK,
             unsigned short* __restrict__ outVt,
             int M, int N, int K)
{
    const int tid  = threadIdx.x;
    const int wave = tid >> 6, lane = tid & 63;
    const int m0 = blockIdx.x * MT, n0 = blockIdx.y * 128;
    const unsigned short* A = (MODE == 4 && blockIdx.y >= 4) ? A1 : A0;

    if constexpr (MT == 128) {
        // ================= 32x32x16 fragment path =================
        __shared__ __align__(16) unsigned short As[2][128 * 32];
        __shared__ __align__(16) unsigned short Bs[2][128 * 32];
        const int l31 = lane & 31, hi5 = lane >> 5, l3 = lane & 3;
        const int wm = (wave & 1) * 64, wn = (wave >> 1) * 64;

        const int srow4 = lane >> 2;
        const int scsw  = ((lane & 3) ^ (srow4 & 3)) * 8;
        const unsigned short* gA = A  + (size_t)(m0 + wave * 32 + srow4) * K + scsw;
        const unsigned short* gB = Bt + (size_t)(n0 + wave * 32 + srow4) * K + scsw;

        f32x16 acc[2][2];
#pragma unroll
        for (int fi = 0; fi < 2; ++fi)
#pragma unroll
            for (int fj = 0; fj < 2; ++fj)
#pragma unroll
                for (int r = 0; r < 16; ++r) acc[fi][fj][r] = 0.f;

        auto stage = [&](int kk, int buf) {
#pragma unroll
            for (int c = 0; c < 2; ++c) {
                gl2lds16(gA + (size_t)c * 16 * K + kk, &As[buf][(wave * 32 + c * 16) * 32]);
                gl2lds16(gB + (size_t)c * 16 * K + kk, &Bs[buf][(wave * 32 + c * 16) * 32]);
            }
        };
        auto compute = [&](int buf) {
#pragma unroll
            for (int h = 0; h < 2; ++h) {
                const int cs = (((h << 1) + hi5) ^ l3) * 8;   // swizzled chunk
                bf16x8 a[2], b[2];
#pragma unroll
                for (int f = 0; f < 2; ++f) {
                    a[f] = *(const bf16x8*)&As[buf][(wm + f * 32 + l31) * 32 + cs];
                    b[f] = *(const bf16x8*)&Bs[buf][(wn + f * 32 + l31) * 32 + cs];
                }
                __builtin_amdgcn_s_setprio(1);
#pragma unroll
                for (int fi = 0; fi < 2; ++fi)
#pragma unroll
                    for (int fj = 0; fj < 2; ++fj)
                        acc[fi][fj] = __builtin_amdgcn_mfma_f32_32x32x16_bf16(
                            a[fi], b[fj], acc[fi][fj], 0, 0, 0);
                __builtin_amdgcn_s_setprio(0);
            }
        };

        stage(0, 0);
        const int NK = K / 32;
        for (int kt = 0; kt < NK; ++kt) {
            const int cur = kt & 1;
            if (kt + 1 < NK) {
                stage((kt + 1) * 32, cur ^ 1);
                asm volatile("s_waitcnt vmcnt(4)" ::: "memory");
            } else {
                asm volatile("s_waitcnt vmcnt(0)" ::: "memory");
            }
            __builtin_amdgcn_sched_barrier(0);
            __builtin_amdgcn_s_barrier();
            __builtin_amdgcn_sched_barrier(0);
            compute(cur);
            asm volatile("s_waitcnt lgkmcnt(0)" ::: "memory");
            __builtin_amdgcn_sched_barrier(0);
            __builtin_amdgcn_s_barrier();
            __builtin_amdgcn_sched_barrier(0);
        }

        // Epilogue. C/D: col = l31, row = (reg&3) + 8*(reg>>2) + 4*hi5.
#pragma unroll
        for (int fi = 0; fi < 2; ++fi) {
#pragma unroll
            for (int fj = 0; fj < 2; ++fj) {
                const int col = n0 + wn + fj * 32 + l31;
                const float bsv = bias[col];
#pragma unroll
                for (int g = 0; g < 4; ++g) {
                    const int row0 = m0 + wm + fi * 32 + 8 * g + 4 * hi5;
                    if (MODE == 4) {
                        if (col < DD) {
#pragma unroll
                            for (int rr = 0; rr < 4; ++rr)
                                outQ[(size_t)(row0 + rr) * DD + col] =
                                    f2b_hu(acc[fi][fj][4 * g + rr] + bsv);
                        } else if (col < 2 * DD) {
#pragma unroll
                            for (int rr = 0; rr < 4; ++rr)
                                outK[(size_t)(row0 + rr) * DD + (col - DD)] =
                                    f2b_hu(acc[fi][fj][4 * g + rr] + bsv);
                        } else {
                            const int feat = col - 2 * DD;
                            const int bb = row0 >> 11;
                            const int n  = row0 & (NN - 1);
                            ushort4 o;
                            o.x = f2b_hu(acc[fi][fj][4 * g + 0] + bsv);
                            o.y = f2b_hu(acc[fi][fj][4 * g + 1] + bsv);
                            o.z = f2b_hu(acc[fi][fj][4 * g + 2] + bsv);
                            o.w = f2b_hu(acc[fi][fj][4 * g + 3] + bsv);
                            *(ushort4*)&outVt[((size_t)bb * DD + feat) * NN + n] = o;
                        }
                    } else {   // MODE 2: gelu, bf16 store
#pragma unroll
                        for (int rr = 0; rr < 4; ++rr) {
                            float v = acc[fi][fj][4 * g + rr] + bsv;
                            float u = 0.7978845608028654f * (v + 0.044715f * v * v * v);
                            float e = __expf(2.0f * u);
                            float t = 1.0f - 2.0f / (e + 1.0f);
                            outB[(size_t)(row0 + rr) * N + col] = f2b_hu(0.5f * v * (1.0f + t));
                        }
                    }
                }
            }
        }
    } else {
        // ================= 16x16x32 fragment path (MT=64) =================
        __shared__ __align__(16) unsigned short As[2][2][MT * 32];
        __shared__ __align__(16) unsigned short Bs[2][2][128 * 32];
        const int quad = lane >> 4, l16 = lane & 15;
        const int MI  = MT / 32;               // 2 accumulator row-tiles
        const int RPW = MT / 4;                // A rows staged per wave
        const int wm = (wave & 1) * (MT / 2), wn = (wave >> 1) * 64;

        const int srow = lane >> 2;
        const int sc8  = (lane & 3) * 8;
        const unsigned short* gA = A  + (size_t)(m0 + wave * RPW + srow) * K + sc8;
        const unsigned short* gB = Bt + (size_t)(n0 + wave * 32  + srow) * K + sc8;

        f32x4 acc[MI][4];
#pragma unroll
        for (int i = 0; i < MI; ++i)
#pragma unroll
            for (int j = 0; j < 4; ++j)
                acc[i][j] = (f32x4){0.f, 0.f, 0.f, 0.f};

        auto stage = [&](int kk, int buf) {
#pragma unroll
            for (int ih = 0; ih < RPW / 16; ++ih)
#pragma unroll
                for (int half = 0; half < 2; ++half)
                    gl2lds16(gA + (size_t)ih * 16 * K + half * 32 + kk,
                             &As[buf][half][(wave * RPW + ih * 16) * 32]);
#pragma unroll
            for (int ih = 0; ih < 2; ++ih)
#pragma unroll
                for (int half = 0; half < 2; ++half)
                    gl2lds16(gB + (size_t)ih * 16 * K + half * 32 + kk,
                             &Bs[buf][half][(wave * 32 + ih * 16) * 32]);
        };
        auto compute = [&](int buf) {
#pragma unroll
            for (int h = 0; h < 2; ++h) {
                bf16x8 a[MI], b[4];
#pragma unroll
                for (int i = 0; i < MI; ++i)
                    a[i] = *(const bf16x8*)&As[buf][h][(wm + i * 16 + l16) * 32 + quad * 8];
#pragma unroll
                for (int j = 0; j < 4; ++j)
                    b[j] = *(const bf16x8*)&Bs[buf][h][(wn + j * 16 + l16) * 32 + quad * 8];
                __builtin_amdgcn_s_setprio(1);
#pragma unroll
                for (int i = 0; i < MI; ++i)
#pragma unroll
                    for (int j = 0; j < 4; ++j)
                        acc[i][j] = __builtin_amdgcn_mfma_f32_16x16x32_bf16(a[i], b[j], acc[i][j], 0, 0, 0);
                __builtin_amdgcn_s_setprio(0);
            }
        };

        stage(0, 0);
        const int NK = K / 64;
        for (int kt = 0; kt < NK; ++kt) {
            const int cur = kt & 1;
            if (kt + 1 < NK) {
                stage((kt + 1) * 64, cur ^ 1);
                asm volatile("s_waitcnt vmcnt(6)" ::: "memory");
            } else {
                asm volatile("s_waitcnt vmcnt(0)" ::: "memory");
            }
            __builtin_amdgcn_sched_barrier(0);
            __builtin_amdgcn_s_barrier();
            __builtin_amdgcn_sched_barrier(0);
            compute(cur);
            asm volatile("s_waitcnt lgkmcnt(0)" ::: "memory");
            __builtin_amdgcn_sched_barrier(0);
            __builtin_amdgcn_s_barrier();
            __builtin_amdgcn_sched_barrier(0);
        }

        // Epilogue. C/D layout: col = lane&15, row = quad*4 + reg.
#pragma unroll
        for (int i = 0; i < MI; ++i) {
#pragma unroll
            for (int j = 0; j < 4; ++j) {
                const int col  = n0 + wn + j * 16 + l16;
                const int row0 = m0 + wm + i * 16 + quad * 4;
                const float bsv = bias[col];
#pragma unroll
                for (int r = 0; r < 4; ++r) {
                    const size_t idx = (size_t)(row0 + r) * N + col;
                    float v = acc[i][j][r] + bsv;
                    if (MODE == 1) {
                        outF[idx] = v + b2f(resB[idx]);
                    } else {   // MODE 3
                        outF[idx] = v + resF[idx];
                    }
                }
            }
        }
    }
}

// ---------------------------------------------------------------------------
// Flash attention v13 (session-best attn, 56.0us measured r9): block =
// (b, h, 128-q tile), 256 THREADS / 4 WAVES, grid 512, 32 q per wave.
// REVERTS v14's 1-barrier triple-buffer (59.1us: stage-after-compute
// serialized against the vmcnt path; the 2nd barrier was cheaper than
// modeled).  Structure:
//  * dbuf LDS K/V via global_load_lds, counted vmcnt(4), raw barriers
//  * linear [64][64] LDS + XOR swizzle via pre-swizzled global source
//  * XCD swizzle, exp2 pre-scale fold, PLD=36, uint2 Pt writes
//  * s_setprio(1) around both MFMA clusters (T5, -6us measured r9)
// ---------------------------------------------------------------------------
#define PLD 36   // Pt row stride in dwords (144B, 16B-aligned)

__global__ __launch_bounds__(256, 2)
void flash_attn_kernel(const unsigned short* __restrict__ Q,
                       const unsigned short* __restrict__ Kb,
                       const unsigned short* __restrict__ Vtg,
                       unsigned short* __restrict__ O)
{
    __shared__ __align__(16) unsigned short Ks[2][64 * 64];    // 2 x 8192 B
    __shared__ __align__(16) unsigned short Vt[2][64 * 64];    // 2 x 8192 B
    __shared__ __align__(16) unsigned int   Pt[4 * 32 * PLD];  // 18432 B

    const int tid  = threadIdx.x;
    const int wave = tid >> 6, lane = tid & 63;
    const int quad = lane >> 4, l16 = lane & 15;
    const int lsw  = l16 & 7;              // read-side XOR key (= row&7)

    // XCD swizzle: 512 blocks on 8 XCDs -> XCD x gets work-ids [x*64,(x+1)*64)
    // = 4 consecutive (b,h) panels; their K/V stays resident in that L2.
    const int bid = (blockIdx.x & 7) * 64 + (blockIdx.x >> 3);
    const int qt = bid & 15;          // 16 q-tiles of 128
    const int bh = bid >> 4;
    const int b  = bh >> 3;
    const int h  = bh & 7;
    const size_t rowbase = (size_t)b * NN * DD;
    const int q0 = qt * 128 + wave * 32;   // this wave's q base (32 q)
    const int hc = h * DH;
    unsigned int* myPt = &Pt[wave * 32 * PLD];

    // staging geometry: each wave stages 16 rows of K and 16 rows (features)
    // of V per tile via 2+2 gl2lds16 calls.  Lane's linear LDS slot within a
    // call: row_local = lane>>3, chunk = lane&7.  Global source column is
    // pre-swizzled: srcChunk = (lane&7) ^ (lane>>3)  (= chunk ^ (row&7)).
    const int srow8 = lane >> 3;                       // 0..7
    const int ssw   = ((lane & 7) ^ srow8) * 8;        // elements
    const unsigned short* gKs = Kb  + rowbase + hc;
    const unsigned short* gVs = Vtg + ((size_t)b * DD + hc) * NN;

    // prologue: stage tile 0 into buffer 0 (async)
#pragma unroll
    for (int c = 0; c < 2; ++c) {
        gl2lds16(gKs + (size_t)(wave * 16 + c * 8 + srow8) * DD + ssw,
                 &Ks[0][(wave * 2 + c) * 512]);
        gl2lds16(gVs + (size_t)(wave * 16 + c * 8 + srow8) * NN + ssw,
                 &Vt[0][(wave * 2 + c) * 512]);
    }

    // hoist Q B-frags, pre-scaled by log2(e)/sqrt(512):
    // q = q0 + t*16 + l16, dh = hh*32 + quad*8
    bf16x8 Qf[2][2];
#pragma unroll
    for (int t = 0; t < 2; ++t)
#pragma unroll
        for (int hh = 0; hh < 2; ++hh) {
            union { bf16x8 v; unsigned short s[8]; unsigned u[4]; } raw, sc;
            raw.v = *(const bf16x8*)&Q[rowbase + (size_t)(q0 + t * 16 + l16) * DD
                                        + hc + hh * 32 + quad * 8];
#pragma unroll
            for (int p = 0; p < 4; ++p)
                sc.u[p] = pk2(b2f(raw.s[2 * p]) * SCALE_QK_E2, b2f(raw.s[2 * p + 1]) * SCALE_QK_E2);
            Qf[t][hh] = sc.v;
        }

    f32x4 Oacc[2][4];   // [q-subtile][dh-tile]: O^T, col=q(l16), row=dh=16t2+4quad+r
#pragma unroll
    for (int t = 0; t < 2; ++t)
#pragma unroll
        for (int t2 = 0; t2 < 4; ++t2) Oacc[t][t2] = (f32x4){0.f, 0.f, 0.f, 0.f};
    float lsum[2] = {0.f, 0.f};

    const int NT = NN / 64;
    for (int kt = 0; kt < NT; ++kt) {
        const int cur = kt & 1;
        // issue NEXT tile's staging into the other buffer, then wait only for
        // the CURRENT tile's 4 calls (issued one compute-phase ago).
        if (kt + 1 < NT) {
            const int nv0 = (kt + 1) * 64;
            const int nb = cur ^ 1;
#pragma unroll
            for (int c = 0; c < 2; ++c) {
                gl2lds16(gKs + (size_t)(nv0 + wave * 16 + c * 8 + srow8) * DD + ssw,
                         &Ks[nb][(wave * 2 + c) * 512]);
                gl2lds16(gVs + (size_t)(wave * 16 + c * 8 + srow8) * NN + nv0 + ssw,
                         &Vt[nb][(wave * 2 + c) * 512]);
            }
            asm volatile("s_waitcnt vmcnt(4)" ::: "memory");
        } else {
            asm volatile("s_waitcnt vmcnt(0)" ::: "memory");
        }
        __builtin_amdgcn_sched_barrier(0);
        __builtin_amdgcn_s_barrier();
        __builtin_amdgcn_sched_barrier(0);

        // ---- S^T: St[t][j] (16 kv x 16 q); each kf feeds 2 MFMAs ----
        __builtin_amdgcn_s_setprio(1);
        f32x4 St[2][4];
#pragma unroll
        for (int t = 0; t < 2; ++t)
#pragma unroll
            for (int j = 0; j < 4; ++j) St[t][j] = (f32x4){0.f, 0.f, 0.f, 0.f};
#pragma unroll
        for (int j = 0; j < 4; ++j) {
#pragma unroll
            for (int hh = 0; hh < 2; ++hh) {
                bf16x8 kf = *(const bf16x8*)&Ks[cur][(j * 16 + l16) * 64
                                                     + (((hh << 2) + quad) ^ lsw) * 8];
#pragma unroll
                for (int t = 0; t < 2; ++t)
                    St[t][j] = __builtin_amdgcn_mfma_f32_16x16x32_bf16(kf, Qf[t][hh], St[t][j], 0, 0, 0);
            }
        }
        __builtin_amdgcn_s_setprio(0);

        // ---- exp2 (scale+log2e pre-folded into Q), scalar lsum, pack P^T ----
#pragma unroll
        for (int t = 0; t < 2; ++t) {
            unsigned int* rowp = &myPt[(t * 16 + l16) * PLD];
#pragma unroll
            for (int j = 0; j < 4; ++j) {
                float p0 = __builtin_amdgcn_exp2f(St[t][j][0]);
                float p1 = __builtin_amdgcn_exp2f(St[t][j][1]);
                float p2 = __builtin_amdgcn_exp2f(St[t][j][2]);
                float p3 = __builtin_amdgcn_exp2f(St[t][j][3]);
                lsum[t] += (p0 + p1) + (p2 + p3);
                uint2 w; w.x = pk2(p0, p1); w.y = pk2(p2, p3);
                *(uint2*)&rowp[j * 8 + quad * 2] = w;
            }
        }

        // ---- O^T += V^T . P^T : each vf feeds 2 MFMAs ----
        __builtin_amdgcn_s_setprio(1);
#pragma unroll
        for (int ks = 0; ks < 2; ++ks) {
            bf16x8 pf[2];
#pragma unroll
            for (int t = 0; t < 2; ++t)
                pf[t] = *(const bf16x8*)&myPt[(t * 16 + l16) * PLD + ks * 16 + quad * 4];
#pragma unroll
            for (int t2 = 0; t2 < 4; ++t2) {
                bf16x8 vf = *(const bf16x8*)&Vt[cur][(t2 * 16 + l16) * 64
                                                     + (((ks << 2) + quad) ^ lsw) * 8];
#pragma unroll
                for (int t = 0; t < 2; ++t)
                    Oacc[t][t2] = __builtin_amdgcn_mfma_f32_16x16x32_bf16(vf, pf[t], Oacc[t][t2], 0, 0, 0);
            }
        }
        __builtin_amdgcn_s_setprio(0);

        // all waves done reading buf[cur] before next iter stages into it
        asm volatile("s_waitcnt lgkmcnt(0)" ::: "memory");
        __builtin_amdgcn_sched_barrier(0);
        __builtin_amdgcn_s_barrier();
        __builtin_amdgcn_sched_barrier(0);
    }

    // reduce lsum across the 4 quads (same q = l16)
#pragma unroll
    for (int t = 0; t < 2; ++t) {
        lsum[t] += __shfl_xor(lsum[t], 16);
        lsum[t] += __shfl_xor(lsum[t], 32);
    }
    const float rl0 = 1.0f / lsum[0], rl1 = 1.0f / lsum[1];

    // transpose O^T -> O via wave-private LDS (reuse Pt), coalesced store
#pragma unroll
    for (int t = 0; t < 2; ++t) {
        const float rl = t ? rl1 : rl0;
        unsigned int* rowp = &myPt[(t * 16 + l16) * PLD];
#pragma unroll
        for (int t2 = 0; t2 < 4; ++t2) {
            uint2 w;
            w.x = pk2(Oacc[t][t2][0] * rl, Oacc[t][t2][1] * rl);
            w.y = pk2(Oacc[t][t2][2] * rl, Oacc[t][t2][3] * rl);
            *(uint2*)&rowp[t2 * 8 + quad * 2] = w;
        }
    }
#pragma unroll
    for (int ii = 0; ii < 4; ++ii) {
        int flat  = lane + ii * 64;       // 0..255 within wave
        int row   = flat >> 3;            // q within wave (0..31)
        int chunk = flat & 7;
        uint4 v = *(const uint4*)&myPt[row * PLD + chunk * 4];
        *(uint4*)&O[rowbase + (size_t)(q0 + row) * DD + hc + chunk * 8] = v;
    }
}

// ---------------------------------------------------------------------------
// Launch
// ---------------------------------------------------------------------------
extern "C" void kernel_launch(void* const* d_in, const int* in_sizes, int n_in,
                              void* d_out, int out_size, void* d_ws, size_t ws_size,
                              hipStream_t stream)
{
    (void)in_sizes; (void)n_in; (void)out_size; (void)ws_size;

    const float* X   = (const float*)d_in[0];
    const float* Y   = (const float*)d_in[1];
    const float* Wq  = (const float*)d_in[2];
    const float* bq  = (const float*)d_in[3];
    const float* Wk  = (const float*)d_in[4];
    const float* bk  = (const float*)d_in[5];
    const float* Wv  = (const float*)d_in[6];
    const float* bv  = (const float*)d_in[7];
    const float* Wm  = (const float*)d_in[8];
    const float* bm  = (const float*)d_in[9];
    const float* g0  = (const float*)d_in[10];
    const float* b0  = (const float*)d_in[11];
    const float* g1  = (const float*)d_in[12];
    const float* b1  = (const float*)d_in[13];
    const float* W1  = (const float*)d_in[14];
    const float* bb1 = (const float*)d_in[15];
    const float* W2  = (const float*)d_in[16];
    const float* bb2 = (const float*)d_in[17];
    float* out = (float*)d_out;

    // workspace carve-up
    char* ws = (char*)d_ws;
    size_t off = 0;
    auto carve = [&](size_t bytes) { void* p = ws + off; off += bytes; return p; };
    const size_t BND2 = (size_t)ROWS * DD * 2;       // 8 MB bf16 [8192,512]

    unsigned short* Xn   = (unsigned short*)carve(BND2);
    unsigned short* Yb   = (unsigned short*)carve(BND2);
    unsigned short* WqkvT= (unsigned short*)carve((size_t)3 * DD * DD * 2);
    unsigned short* WmT  = (unsigned short*)carve((size_t)DD * DD * 2);
    unsigned short* W1T  = (unsigned short*)carve((size_t)DD * DFF * 2);
    unsigned short* W2T  = (unsigned short*)carve((size_t)DFF * DD * 2);
    float*          bqkv = (float*)carve(1536 * 4);
    unsigned short* Qb   = (unsigned short*)carve(BND2);
    unsigned short* Kbf  = (unsigned short*)carve(BND2);
    unsigned short* Vtg  = (unsigned short*)carve(BND2);  // V^T [b*512+feat][token]
    float*          Hx   = (float*)carve((size_t)ROWS * DD * 4);
    unsigned short* G    = (unsigned short*)carve((size_t)ROWS * DFF * 2);
    unsigned short* Mh   = Xn;   // reuse: Xn dead after QKV
    unsigned short* Hn   = Yb;   // reuse: Yb dead after QKV

    // 1+2. merged preprocessing: LN(X), cast(Y), all transposes, bias concat
    preprocess_kernel<<<NB_LN + NB_CAST + NB_TR + NB_BIAS, 256, 0, stream>>>(
        X, g0, b0, Xn, Y, Yb,
        Wq, Wk, Wv, Wm, W1, W2, WqkvT, WmT, W1T, W2T,
        bq, bk, bv, bqkv);

    // 3. fused QKV projection (768 blocks, 3/CU; 32x32 frags, dbuf BK=32)
    gemm_bt<4, 128><<<dim3(ROWS / 128, 12), 256, 0, stream>>>(
        Xn, Yb, WqkvT, bqkv, nullptr, nullptr, nullptr, nullptr,
        Qb, Kbf, Vtg, ROWS, 3 * DD, DD);

    // 4. attention (512 blocks of 256 threads: b,h,16 q-tiles of 128)
    flash_attn_kernel<<<BB * HH * (NN / 128), 256, 0, stream>>>(Qb, Kbf, Vtg, Mh);

    // 5. head mix + residual (Q) -> Hx fp32   (MT=64 dbuf -> 512 blocks, 2/CU)
    gemm_bt<1, 64><<<dim3(ROWS / 64, DD / 128), 256, 0, stream>>>(
        Mh, nullptr, WmT, bm, Qb, nullptr, nullptr, Hx,
        nullptr, nullptr, nullptr, ROWS, DD, DD);

    // 6. LN(Hx) -> Hn bf16
    ln_kernel<<<ROWS, 256, 0, stream>>>(Hx, g1, b1, Hn);

    // 7. FFN1 + fast gelu -> G bf16  (1024 blocks, 4/CU; 32x32 frags, BK=32)
    gemm_bt<2, 128><<<dim3(ROWS / 128, DFF / 128), 256, 0, stream>>>(
        Hn, nullptr, W1T, bb1, nullptr, nullptr, G, nullptr,
        nullptr, nullptr, nullptr, ROWS, DFF, DD);

    // 8. FFN2 + residual (Hx) -> out fp32  (MT=64 dbuf -> 512 blocks, 2/CU)
    gemm_bt<3, 64><<<dim3(ROWS / 64, DD / 128), 256, 0, stream>>>(
        G, nullptr, W2T, bb2, nullptr, Hx, nullptr, out,
        nullptr, nullptr, nullptr, ROWS, DD, DFF);
}

// Round 12
// 271.908 us; speedup vs baseline: 1.0254x; 1.0142x over previous
//
#include <hip/hip_runtime.h>
#include <cmath>

// ---------------------------------------------------------------------------
// Types / helpers
// ---------------------------------------------------------------------------
typedef __attribute__((ext_vector_type(8))) short bf16x8;   // 8 bf16 = 4 VGPRs
typedef __attribute__((ext_vector_type(4))) float f32x4;
typedef __attribute__((ext_vector_type(16))) float f32x16;  // 32x32 MFMA acc

__device__ __forceinline__ unsigned short f2b(float f) {   // RNE (cold paths)
    union { float f; unsigned u; } c; c.f = f;
    unsigned r = (c.u + 0x7FFFu + ((c.u >> 16) & 1u)) >> 16;
    return (unsigned short)r;
}
__device__ __forceinline__ unsigned short f2b_hu(float f) { // round-half-up, 2 VALU
    union { float f; unsigned u; } c; c.f = f;
    return (unsigned short)((c.u + 0x8000u) >> 16);
}
// single-instruction 2xf32 -> 2xbf16 pack (RNE); no builtin on gfx950, inline
// asm per guide T12 recipe (HW-verified m214v22).  Replaces the 5-VALU-op
// hand pack on the attn softmax critical path.
__device__ __forceinline__ unsigned cvtpk2(float a, float b) {
    unsigned r;
    asm("v_cvt_pk_bf16_f32 %0, %1, %2" : "=v"(r) : "v"(a), "v"(b));
    return r;
}
__device__ __forceinline__ float b2f(unsigned short h) {
    union { unsigned u; float f; } c; c.u = ((unsigned)h) << 16;
    return c.f;
}

// async global->LDS 16B (wave-uniform LDS base + lane*16; global src per-lane)
__device__ __forceinline__ void gl2lds16(const unsigned short* g, unsigned short* l) {
    __builtin_amdgcn_global_load_lds(
        (const __attribute__((address_space(1))) unsigned int*)(g),
        (__attribute__((address_space(3))) unsigned int*)(l),
        16, 0, 0);
}

// Problem constants
#define BB   4
#define NN   2048
#define DD   512
#define HH   8
#define DH   64
#define DFF  2048
#define ROWS (BB * NN)          // 8192
#define SCALE_QK 0.044194173824159216f   // 1/sqrt(512)
// 1/sqrt(512) * log2(e): exp(S) == exp2(S') with S' from pre-scaled Q
#define SCALE_QK_E2 0.06376112595042793f

// ---------------------------------------------------------------------------
// LayerNorm row body (fp32 in -> bf16 out), 256 threads per 512-row.
// ---------------------------------------------------------------------------
__device__ __forceinline__ void ln_row_body(const float* __restrict__ X,
                                            const float* __restrict__ g,
                                            const float* __restrict__ be,
                                            unsigned short* __restrict__ out,
                                            int row, int tid, float* sred)
{
    const float* x = X + (size_t)row * DD;
    float x0 = x[tid], x1 = x[tid + 256];
    float s = x0 + x1, sq = x0 * x0 + x1 * x1;
#pragma unroll
    for (int off = 32; off; off >>= 1) {
        s  += __shfl_down(s,  off);
        sq += __shfl_down(sq, off);
    }
    const int wid = tid >> 6;
    if ((tid & 63) == 0) { sred[wid] = s; sred[4 + wid] = sq; }
    __syncthreads();
    float ts = 0.f, tq = 0.f;
#pragma unroll
    for (int i = 0; i < 4; ++i) { ts += sred[i]; tq += sred[4 + i]; }
    const float mean = ts * (1.0f / DD);
    const float var  = tq * (1.0f / DD) - mean * mean;
    const float rinv = rsqrtf(var + 1e-5f);
    unsigned short* o = out + (size_t)row * DD;
    o[tid]       = f2b((x0 - mean) * rinv * g[tid]       + be[tid]);
    o[tid + 256] = f2b((x1 - mean) * rinv * g[tid + 256] + be[tid + 256]);
}

__global__ __launch_bounds__(256)
void ln_kernel(const float* __restrict__ X, const float* __restrict__ g,
               const float* __restrict__ be, unsigned short* __restrict__ out)
{
    __shared__ float sred[8];
    ln_row_body(X, g, be, out, blockIdx.x, threadIdx.x, sred);
}

// ---------------------------------------------------------------------------
// MERGED preprocessing (one launch instead of 4): block-range dispatch.
//   [0, 8192)            : LN(X) -> Xn bf16
//   [8192, 10240)        : cast Y -> Yb bf16 (4 elems/thread)
//   [10240, 13312)       : all weight transposes (3072 32x32 tiles)
//   [13312, 13318)       : bias concat bq|bk|bv -> bqkv
// ---------------------------------------------------------------------------
#define NB_LN   ROWS
#define NB_CAST (ROWS * DD / 4 / 256)
#define NB_TR   3072
#define NB_BIAS 6

__global__ __launch_bounds__(256)
void preprocess_kernel(const float* __restrict__ X, const float* __restrict__ g0,
                       const float* __restrict__ b0, unsigned short* __restrict__ Xn,
                       const float* __restrict__ Y, unsigned short* __restrict__ Yb,
                       const float* __restrict__ Wq, const float* __restrict__ Wk,
                       const float* __restrict__ Wv, const float* __restrict__ Wm,
                       const float* __restrict__ W1, const float* __restrict__ W2,
                       unsigned short* __restrict__ WqkvT, unsigned short* __restrict__ WmT,
                       unsigned short* __restrict__ W1T, unsigned short* __restrict__ W2T,
                       const float* __restrict__ bq, const float* __restrict__ bk,
                       const float* __restrict__ bv, float* __restrict__ bqkv)
{
    __shared__ float smem[32 * 33];
    const int blk = blockIdx.x;
    const int tid = threadIdx.x;

    if (blk < NB_LN) {
        ln_row_body(X, g0, b0, Xn, blk, tid, smem);
    } else if (blk < NB_LN + NB_CAST) {
        int i = (blk - NB_LN) * 256 + tid;
        float4 v = ((const float4*)Y)[i];
        ushort4 o;
        o.x = f2b(v.x); o.y = f2b(v.y); o.z = f2b(v.z); o.w = f2b(v.w);
        ((ushort4*)Yb)[i] = o;
    } else if (blk < NB_LN + NB_CAST + NB_TR) {
        const int t = blk - (NB_LN + NB_CAST);
        float (*tile)[33] = (float(*)[33])smem;
        const float* W; unsigned short* Wt; int K, Nn, n0, k0;
        if (t < 1024) {
            W = W1; Wt = W1T; K = DD; Nn = DFF;
            n0 = (t & 63) * 32; k0 = (t >> 6) * 32;
        } else if (t < 2048) {
            int u = t - 1024;
            W = W2; Wt = W2T; K = DFF; Nn = DD;
            n0 = (u & 15) * 32; k0 = (u >> 4) * 32;
        } else {
            int u = t - 2048;
            int m = u >> 8;            // 0..3 : Wq,Wk,Wv,Wm
            int v = u & 255;
            K = DD; Nn = DD;
            n0 = (v & 15) * 32; k0 = (v >> 4) * 32;
            if (m == 0)      { W = Wq; Wt = WqkvT; }
            else if (m == 1) { W = Wk; Wt = WqkvT + (size_t)DD * DD; }
            else if (m == 2) { W = Wv; Wt = WqkvT + (size_t)2 * DD * DD; }
            else             { W = Wm; Wt = WmT; }
        }
        const int tx = tid & 31, ty = tid >> 5;  // ty 0..7
#pragma unroll
        for (int i = 0; i < 4; ++i)
            tile[ty + i * 8][tx] = W[(size_t)(k0 + ty + i * 8) * Nn + n0 + tx];
        __syncthreads();
#pragma unroll
        for (int i = 0; i < 4; ++i)
            Wt[(size_t)(n0 + ty + i * 8) * K + k0 + tx] = f2b(tile[tx][ty + i * 8]);
    } else {
        int i = (blk - (NB_LN + NB_CAST + NB_TR)) * 256 + tid;   // 0..1535
        float v = (i < 512) ? bq[i] : (i < 1024) ? bk[i - 512] : bv[i - 1024];
        bqkv[i] = v;
    }
}

// ---------------------------------------------------------------------------
// GEMM: C[M,N] = A[M,K] @ Bt[N,K]^T + bias, bf16 in, fp32 accumulate.
// 256 threads (4 waves), double-buffered counted-vmcnt pipeline, with
// s_setprio(1) around the MFMA clusters (T5; isolated -2.2us in r10).
// MT=128: 32x32x16 MFMAs, BK=32, XOR-swizzled [128][32] LDS (both sides).
// MT=64 : 16x16x32 MFMAs, BK=64 (original fragment path).
// MODE 1: += bf16 residual (resB), store fp32 (outF)            [mix]
// MODE 2: fast-tanh gelu, store bf16 (outB)                     [FFN1]
// MODE 3: += fp32 residual (resF), store fp32 (outF)            [FFN2]
// MODE 4: fused QKV, N=1536 (MT=128): col<512->Qb, <1024->Kbf, else V
//         transposed into Vtg[b*512+feat][token]; A=(by<4)?A0:A1.
// ---------------------------------------------------------------------------
template <int MODE, int MT>
__global__ __launch_bounds__(256, (MT == 128) ? 4 : 2)
void gemm_bt(const unsigned short* __restrict__ A0, const unsigned short* __restrict__ A1,
             const unsigned short* __restrict__ Bt,
             const float* __restrict__ bias,
             const unsigned short* __restrict__ resB, const float* __restrict__ resF,
             unsigned short* __restrict__ outB, float* __restrict__ outF,
             unsigned short* __restrict__ outQ, unsigned short* __restrict__ outK,
             unsigned short* __restrict__ outVt,
             int M, int N, int K)
{
    const int tid  = threadIdx.x;
    const int wave = tid >> 6, lane = tid & 63;
    const int m0 = blockIdx.x * MT, n0 = blockIdx.y * 128;
    const unsigned short* A = (MODE == 4 && blockIdx.y >= 4) ? A1 : A0;

    if constexpr (MT == 128) {
        // ================= 32x32x16 fragment path =================
        __shared__ __align__(16) unsigned short As[2][128 * 32];
        __shared__ __align__(16) unsigned short Bs[2][128 * 32];
        const int l31 = lane & 31, hi5 = lane >> 5, l3 = lane & 3;
        const int wm = (wave & 1) * 64, wn = (wave >> 1) * 64;

        const int srow4 = lane >> 2;
        const int scsw  = ((lane & 3) ^ (srow4 & 3)) * 8;
        const unsigned short* gA = A  + (size_t)(m0 + wave * 32 + srow4) * K + scsw;
        const unsigned short* gB = Bt + (size_t)(n0 + wave * 32 + srow4) * K + scsw;

        f32x16 acc[2][2];
#pragma unroll
        for (int fi = 0; fi < 2; ++fi)
#pragma unroll
            for (int fj = 0; fj < 2; ++fj)
#pragma unroll
                for (int r = 0; r < 16; ++r) acc[fi][fj][r] = 0.f;

        auto stage = [&](int kk, int buf) {
#pragma unroll
            for (int c = 0; c < 2; ++c) {
                gl2lds16(gA + (size_t)c * 16 * K + kk, &As[buf][(wave * 32 + c * 16) * 32]);
                gl2lds16(gB + (size_t)c * 16 * K + kk, &Bs[buf][(wave * 32 + c * 16) * 32]);
            }
        };
        auto compute = [&](int buf) {
#pragma unroll
            for (int h = 0; h < 2; ++h) {
                const int cs = (((h << 1) + hi5) ^ l3) * 8;   // swizzled chunk
                bf16x8 a[2], b[2];
#pragma unroll
                for (int f = 0; f < 2; ++f) {
                    a[f] = *(const bf16x8*)&As[buf][(wm + f * 32 + l31) * 32 + cs];
                    b[f] = *(const bf16x8*)&Bs[buf][(wn + f * 32 + l31) * 32 + cs];
                }
                __builtin_amdgcn_s_setprio(1);
#pragma unroll
                for (int fi = 0; fi < 2; ++fi)
#pragma unroll
                    for (int fj = 0; fj < 2; ++fj)
                        acc[fi][fj] = __builtin_amdgcn_mfma_f32_32x32x16_bf16(
                            a[fi], b[fj], acc[fi][fj], 0, 0, 0);
                __builtin_amdgcn_s_setprio(0);
            }
        };

        stage(0, 0);
        const int NK = K / 32;
        for (int kt = 0; kt < NK; ++kt) {
            const int cur = kt & 1;
            if (kt + 1 < NK) {
                stage((kt + 1) * 32, cur ^ 1);
                asm volatile("s_waitcnt vmcnt(4)" ::: "memory");
            } else {
                asm volatile("s_waitcnt vmcnt(0)" ::: "memory");
            }
            __builtin_amdgcn_sched_barrier(0);
            __builtin_amdgcn_s_barrier();
            __builtin_amdgcn_sched_barrier(0);
            compute(cur);
            asm volatile("s_waitcnt lgkmcnt(0)" ::: "memory");
            __builtin_amdgcn_sched_barrier(0);
            __builtin_amdgcn_s_barrier();
            __builtin_amdgcn_sched_barrier(0);
        }

        // Epilogue. C/D: col = l31, row = (reg&3) + 8*(reg>>2) + 4*hi5.
#pragma unroll
        for (int fi = 0; fi < 2; ++fi) {
#pragma unroll
            for (int fj = 0; fj < 2; ++fj) {
                const int col = n0 + wn + fj * 32 + l31;
                const float bsv = bias[col];
#pragma unroll
                for (int g = 0; g < 4; ++g) {
                    const int row0 = m0 + wm + fi * 32 + 8 * g + 4 * hi5;
                    if (MODE == 4) {
                        if (col < DD) {
#pragma unroll
                            for (int rr = 0; rr < 4; ++rr)
                                outQ[(size_t)(row0 + rr) * DD + col] =
                                    f2b_hu(acc[fi][fj][4 * g + rr] + bsv);
                        } else if (col < 2 * DD) {
#pragma unroll
                            for (int rr = 0; rr < 4; ++rr)
                                outK[(size_t)(row0 + rr) * DD + (col - DD)] =
                                    f2b_hu(acc[fi][fj][4 * g + rr] + bsv);
                        } else {
                            const int feat = col - 2 * DD;
                            const int bb = row0 >> 11;
                            const int n  = row0 & (NN - 1);
                            ushort4 o;
                            o.x = f2b_hu(acc[fi][fj][4 * g + 0] + bsv);
                            o.y = f2b_hu(acc[fi][fj][4 * g + 1] + bsv);
                            o.z = f2b_hu(acc[fi][fj][4 * g + 2] + bsv);
                            o.w = f2b_hu(acc[fi][fj][4 * g + 3] + bsv);
                            *(ushort4*)&outVt[((size_t)bb * DD + feat) * NN + n] = o;
                        }
                    } else {   // MODE 2: gelu, bf16 store
#pragma unroll
                        for (int rr = 0; rr < 4; ++rr) {
                            float v = acc[fi][fj][4 * g + rr] + bsv;
                            float u = 0.7978845608028654f * (v + 0.044715f * v * v * v);
                            float e = __expf(2.0f * u);
                            float t = 1.0f - 2.0f / (e + 1.0f);
                            outB[(size_t)(row0 + rr) * N + col] = f2b_hu(0.5f * v * (1.0f + t));
                        }
                    }
                }
            }
        }
    } else {
        // ================= 16x16x32 fragment path (MT=64) =================
        __shared__ __align__(16) unsigned short As[2][2][MT * 32];
        __shared__ __align__(16) unsigned short Bs[2][2][128 * 32];
        const int quad = lane >> 4, l16 = lane & 15;
        const int MI  = MT / 32;               // 2 accumulator row-tiles
        const int RPW = MT / 4;                // A rows staged per wave
        const int wm = (wave & 1) * (MT / 2), wn = (wave >> 1) * 64;

        const int srow = lane >> 2;
        const int sc8  = (lane & 3) * 8;
        const unsigned short* gA = A  + (size_t)(m0 + wave * RPW + srow) * K + sc8;
        const unsigned short* gB = Bt + (size_t)(n0 + wave * 32  + srow) * K + sc8;

        f32x4 acc[MI][4];
#pragma unroll
        for (int i = 0; i < MI; ++i)
#pragma unroll
            for (int j = 0; j < 4; ++j)
                acc[i][j] = (f32x4){0.f, 0.f, 0.f, 0.f};

        auto stage = [&](int kk, int buf) {
#pragma unroll
            for (int ih = 0; ih < RPW / 16; ++ih)
#pragma unroll
                for (int half = 0; half < 2; ++half)
                    gl2lds16(gA + (size_t)ih * 16 * K + half * 32 + kk,
                             &As[buf][half][(wave * RPW + ih * 16) * 32]);
#pragma unroll
            for (int ih = 0; ih < 2; ++ih)
#pragma unroll
                for (int half = 0; half < 2; ++half)
                    gl2lds16(gB + (size_t)ih * 16 * K + half * 32 + kk,
                             &Bs[buf][half][(wave * 32 + ih * 16) * 32]);
        };
        auto compute = [&](int buf) {
#pragma unroll
            for (int h = 0; h < 2; ++h) {
                bf16x8 a[MI], b[4];
#pragma unroll
                for (int i = 0; i < MI; ++i)
                    a[i] = *(const bf16x8*)&As[buf][h][(wm + i * 16 + l16) * 32 + quad * 8];
#pragma unroll
                for (int j = 0; j < 4; ++j)
                    b[j] = *(const bf16x8*)&Bs[buf][h][(wn + j * 16 + l16) * 32 + quad * 8];
                __builtin_amdgcn_s_setprio(1);
#pragma unroll
                for (int i = 0; i < MI; ++i)
#pragma unroll
                    for (int j = 0; j < 4; ++j)
                        acc[i][j] = __builtin_amdgcn_mfma_f32_16x16x32_bf16(a[i], b[j], acc[i][j], 0, 0, 0);
                __builtin_amdgcn_s_setprio(0);
            }
        };

        stage(0, 0);
        const int NK = K / 64;
        for (int kt = 0; kt < NK; ++kt) {
            const int cur = kt & 1;
            if (kt + 1 < NK) {
                stage((kt + 1) * 64, cur ^ 1);
                asm volatile("s_waitcnt vmcnt(6)" ::: "memory");
            } else {
                asm volatile("s_waitcnt vmcnt(0)" ::: "memory");
            }
            __builtin_amdgcn_sched_barrier(0);
            __builtin_amdgcn_s_barrier();
            __builtin_amdgcn_sched_barrier(0);
            compute(cur);
            asm volatile("s_waitcnt lgkmcnt(0)" ::: "memory");
            __builtin_amdgcn_sched_barrier(0);
            __builtin_amdgcn_s_barrier();
            __builtin_amdgcn_sched_barrier(0);
        }

        // Epilogue. C/D layout: col = lane&15, row = quad*4 + reg.
#pragma unroll
        for (int i = 0; i < MI; ++i) {
#pragma unroll
            for (int j = 0; j < 4; ++j) {
                const int col  = n0 + wn + j * 16 + l16;
                const int row0 = m0 + wm + i * 16 + quad * 4;
                const float bsv = bias[col];
#pragma unroll
                for (int r = 0; r < 4; ++r) {
                    const size_t idx = (size_t)(row0 + r) * N + col;
                    float v = acc[i][j][r] + bsv;
                    if (MODE == 1) {
                        outF[idx] = v + b2f(resB[idx]);
                    } else {   // MODE 3
                        outF[idx] = v + resF[idx];
                    }
                }
            }
        }
    }
}

// ---------------------------------------------------------------------------
// Flash attention v15 = v13 (r11 config, 58.5us) with the softmax-path
// bf16 packing switched from the 5-VALU-op half-up pk2 to single-instruction
// v_cvt_pk_bf16_f32 (RNE).  The softmax phase sits SERIALLY between the two
// MFMA clusters and VALU is the top pipe (40%); 16 packs/iter at 5 ops -> 1
// op each removes ~64 VALU cyc/wave-iter from the critical path.  Also
// applied to the Q pre-scale hoist and O-transpose (cold).
// Structure otherwise identical to v13:
//  * dbuf LDS K/V via global_load_lds, counted vmcnt(4), raw barriers
//  * linear [64][64] LDS + XOR swizzle via pre-swizzled global source
//  * XCD swizzle, exp2 pre-scale fold, PLD=36, setprio on MFMA clusters
// ---------------------------------------------------------------------------
#define PLD 36   // Pt row stride in dwords (144B, 16B-aligned)

__global__ __launch_bounds__(256, 2)
void flash_attn_kernel(const unsigned short* __restrict__ Q,
                       const unsigned short* __restrict__ Kb,
                       const unsigned short* __restrict__ Vtg,
                       unsigned short* __restrict__ O)
{
    __shared__ __align__(16) unsigned short Ks[2][64 * 64];    // 2 x 8192 B
    __shared__ __align__(16) unsigned short Vt[2][64 * 64];    // 2 x 8192 B
    __shared__ __align__(16) unsigned int   Pt[4 * 32 * PLD];  // 18432 B

    const int tid  = threadIdx.x;
    const int wave = tid >> 6, lane = tid & 63;
    const int quad = lane >> 4, l16 = lane & 15;
    const int lsw  = l16 & 7;              // read-side XOR key (= row&7)

    // XCD swizzle: 512 blocks on 8 XCDs -> XCD x gets work-ids [x*64,(x+1)*64)
    // = 4 consecutive (b,h) panels; their K/V stays resident in that L2.
    const int bid = (blockIdx.x & 7) * 64 + (blockIdx.x >> 3);
    const int qt = bid & 15;          // 16 q-tiles of 128
    const int bh = bid >> 4;
    const int b  = bh >> 3;
    const int h  = bh & 7;
    const size_t rowbase = (size_t)b * NN * DD;
    const int q0 = qt * 128 + wave * 32;   // this wave's q base (32 q)
    const int hc = h * DH;
    unsigned int* myPt = &Pt[wave * 32 * PLD];

    // staging geometry: each wave stages 16 rows of K and 16 rows (features)
    // of V per tile via 2+2 gl2lds16 calls.  Lane's linear LDS slot within a
    // call: row_local = lane>>3, chunk = lane&7.  Global source column is
    // pre-swizzled: srcChunk = (lane&7) ^ (lane>>3)  (= chunk ^ (row&7)).
    const int srow8 = lane >> 3;                       // 0..7
    const int ssw   = ((lane & 7) ^ srow8) * 8;        // elements
    const unsigned short* gKs = Kb  + rowbase + hc;
    const unsigned short* gVs = Vtg + ((size_t)b * DD + hc) * NN;

    // prologue: stage tile 0 into buffer 0 (async)
#pragma unroll
    for (int c = 0; c < 2; ++c) {
        gl2lds16(gKs + (size_t)(wave * 16 + c * 8 + srow8) * DD + ssw,
                 &Ks[0][(wave * 2 + c) * 512]);
        gl2lds16(gVs + (size_t)(wave * 16 + c * 8 + srow8) * NN + ssw,
                 &Vt[0][(wave * 2 + c) * 512]);
    }

    // hoist Q B-frags, pre-scaled by log2(e)/sqrt(512):
    // q = q0 + t*16 + l16, dh = hh*32 + quad*8
    bf16x8 Qf[2][2];
#pragma unroll
    for (int t = 0; t < 2; ++t)
#pragma unroll
        for (int hh = 0; hh < 2; ++hh) {
            union { bf16x8 v; unsigned short s[8]; unsigned u[4]; } raw, sc;
            raw.v = *(const bf16x8*)&Q[rowbase + (size_t)(q0 + t * 16 + l16) * DD
                                        + hc + hh * 32 + quad * 8];
#pragma unroll
            for (int p = 0; p < 4; ++p)
                sc.u[p] = cvtpk2(b2f(raw.s[2 * p]) * SCALE_QK_E2,
                                 b2f(raw.s[2 * p + 1]) * SCALE_QK_E2);
            Qf[t][hh] = sc.v;
        }

    f32x4 Oacc[2][4];   // [q-subtile][dh-tile]: O^T, col=q(l16), row=dh=16t2+4quad+r
#pragma unroll
    for (int t = 0; t < 2; ++t)
#pragma unroll
        for (int t2 = 0; t2 < 4; ++t2) Oacc[t][t2] = (f32x4){0.f, 0.f, 0.f, 0.f};
    float lsum[2] = {0.f, 0.f};

    const int NT = NN / 64;
    for (int kt = 0; kt < NT; ++kt) {
        const int cur = kt & 1;
        // issue NEXT tile's staging into the other buffer, then wait only for
        // the CURRENT tile's 4 calls (issued one compute-phase ago).
        if (kt + 1 < NT) {
            const int nv0 = (kt + 1) * 64;
            const int nb = cur ^ 1;
#pragma unroll
            for (int c = 0; c < 2; ++c) {
                gl2lds16(gKs + (size_t)(nv0 + wave * 16 + c * 8 + srow8) * DD + ssw,
                         &Ks[nb][(wave * 2 + c) * 512]);
                gl2lds16(gVs + (size_t)(wave * 16 + c * 8 + srow8) * NN + nv0 + ssw,
                         &Vt[nb][(wave * 2 + c) * 512]);
            }
            asm volatile("s_waitcnt vmcnt(4)" ::: "memory");
        } else {
            asm volatile("s_waitcnt vmcnt(0)" ::: "memory");
        }
        __builtin_amdgcn_sched_barrier(0);
        __builtin_amdgcn_s_barrier();
        __builtin_amdgcn_sched_barrier(0);

        // ---- S^T: St[t][j] (16 kv x 16 q); each kf feeds 2 MFMAs ----
        __builtin_amdgcn_s_setprio(1);
        f32x4 St[2][4];
#pragma unroll
        for (int t = 0; t < 2; ++t)
#pragma unroll
            for (int j = 0; j < 4; ++j) St[t][j] = (f32x4){0.f, 0.f, 0.f, 0.f};
#pragma unroll
        for (int j = 0; j < 4; ++j) {
#pragma unroll
            for (int hh = 0; hh < 2; ++hh) {
                bf16x8 kf = *(const bf16x8*)&Ks[cur][(j * 16 + l16) * 64
                                                     + (((hh << 2) + quad) ^ lsw) * 8];
#pragma unroll
                for (int t = 0; t < 2; ++t)
                    St[t][j] = __builtin_amdgcn_mfma_f32_16x16x32_bf16(kf, Qf[t][hh], St[t][j], 0, 0, 0);
            }
        }
        __builtin_amdgcn_s_setprio(0);

        // ---- exp2 (scale+log2e pre-folded into Q), scalar lsum,
        //      pack P^T via single-instr v_cvt_pk_bf16_f32 ----
#pragma unroll
        for (int t = 0; t < 2; ++t) {
            unsigned int* rowp = &myPt[(t * 16 + l16) * PLD];
#pragma unroll
            for (int j = 0; j < 4; ++j) {
                float p0 = __builtin_amdgcn_exp2f(St[t][j][0]);
                float p1 = __builtin_amdgcn_exp2f(St[t][j][1]);
                float p2 = __builtin_amdgcn_exp2f(St[t][j][2]);
                float p3 = __builtin_amdgcn_exp2f(St[t][j][3]);
                lsum[t] += (p0 + p1) + (p2 + p3);
                uint2 w; w.x = cvtpk2(p0, p1); w.y = cvtpk2(p2, p3);
                *(uint2*)&rowp[j * 8 + quad * 2] = w;
            }
        }

        // ---- O^T += V^T . P^T : each vf feeds 2 MFMAs ----
        __builtin_amdgcn_s_setprio(1);
#pragma unroll
        for (int ks = 0; ks < 2; ++ks) {
            bf16x8 pf[2];
#pragma unroll
            for (int t = 0; t < 2; ++t)
                pf[t] = *(const bf16x8*)&myPt[(t * 16 + l16) * PLD + ks * 16 + quad * 4];
#pragma unroll
            for (int t2 = 0; t2 < 4; ++t2) {
                bf16x8 vf = *(const bf16x8*)&Vt[cur][(t2 * 16 + l16) * 64
                                                     + (((ks << 2) + quad) ^ lsw) * 8];
#pragma unroll
                for (int t = 0; t < 2; ++t)
                    Oacc[t][t2] = __builtin_amdgcn_mfma_f32_16x16x32_bf16(vf, pf[t], Oacc[t][t2], 0, 0, 0);
            }
        }
        __builtin_amdgcn_s_setprio(0);

        // all waves done reading buf[cur] before next iter stages into it
        asm volatile("s_waitcnt lgkmcnt(0)" ::: "memory");
        __builtin_amdgcn_sched_barrier(0);
        __builtin_amdgcn_s_barrier();
        __builtin_amdgcn_sched_barrier(0);
    }

    // reduce lsum across the 4 quads (same q = l16)
#pragma unroll
    for (int t = 0; t < 2; ++t) {
        lsum[t] += __shfl_xor(lsum[t], 16);
        lsum[t] += __shfl_xor(lsum[t], 32);
    }
    const float rl0 = 1.0f / lsum[0], rl1 = 1.0f / lsum[1];

    // transpose O^T -> O via wave-private LDS (reuse Pt), coalesced store
#pragma unroll
    for (int t = 0; t < 2; ++t) {
        const float rl = t ? rl1 : rl0;
        unsigned int* rowp = &myPt[(t * 16 + l16) * PLD];
#pragma unroll
        for (int t2 = 0; t2 < 4; ++t2) {
            uint2 w;
            w.x = cvtpk2(Oacc[t][t2][0] * rl, Oacc[t][t2][1] * rl);
            w.y = cvtpk2(Oacc[t][t2][2] * rl, Oacc[t][t2][3] * rl);
            *(uint2*)&rowp[t2 * 8 + quad * 2] = w;
        }
    }
#pragma unroll
    for (int ii = 0; ii < 4; ++ii) {
        int flat  = lane + ii * 64;       // 0..255 within wave
        int row   = flat >> 3;            // q within wave (0..31)
        int chunk = flat & 7;
        uint4 v = *(const uint4*)&myPt[row * PLD + chunk * 4];
        *(uint4*)&O[rowbase + (size_t)(q0 + row) * DD + hc + chunk * 8] = v;
    }
}

// ---------------------------------------------------------------------------
// Launch
// ---------------------------------------------------------------------------
extern "C" void kernel_launch(void* const* d_in, const int* in_sizes, int n_in,
                              void* d_out, int out_size, void* d_ws, size_t ws_size,
                              hipStream_t stream)
{
    (void)in_sizes; (void)n_in; (void)out_size; (void)ws_size;

    const float* X   = (const float*)d_in[0];
    const float* Y   = (const float*)d_in[1];
    const float* Wq  = (const float*)d_in[2];
    const float* bq  = (const float*)d_in[3];
    const float* Wk  = (const float*)d_in[4];
    const float* bk  = (const float*)d_in[5];
    const float* Wv  = (const float*)d_in[6];
    const float* bv  = (const float*)d_in[7];
    const float* Wm  = (const float*)d_in[8];
    const float* bm  = (const float*)d_in[9];
    const float* g0  = (const float*)d_in[10];
    const float* b0  = (const float*)d_in[11];
    const float* g1  = (const float*)d_in[12];
    const float* b1  = (const float*)d_in[13];
    const float* W1  = (const float*)d_in[14];
    const float* bb1 = (const float*)d_in[15];
    const float* W2  = (const float*)d_in[16];
    const float* bb2 = (const float*)d_in[17];
    float* out = (float*)d_out;

    // workspace carve-up
    char* ws = (char*)d_ws;
    size_t off = 0;
    auto carve = [&](size_t bytes) { void* p = ws + off; off += bytes; return p; };
    const size_t BND2 = (size_t)ROWS * DD * 2;       // 8 MB bf16 [8192,512]

    unsigned short* Xn   = (unsigned short*)carve(BND2);
    unsigned short* Yb   = (unsigned short*)carve(BND2);
    unsigned short* WqkvT= (unsigned short*)carve((size_t)3 * DD * DD * 2);
    unsigned short* WmT  = (unsigned short*)carve((size_t)DD * DD * 2);
    unsigned short* W1T  = (unsigned short*)carve((size_t)DD * DFF * 2);
    unsigned short* W2T  = (unsigned short*)carve((size_t)DFF * DD * 2);
    float*          bqkv = (float*)carve(1536 * 4);
    unsigned short* Qb   = (unsigned short*)carve(BND2);
    unsigned short* Kbf  = (unsigned short*)carve(BND2);
    unsigned short* Vtg  = (unsigned short*)carve(BND2);  // V^T [b*512+feat][token]
    float*          Hx   = (float*)carve((size_t)ROWS * DD * 4);
    unsigned short* G    = (unsigned short*)carve((size_t)ROWS * DFF * 2);
    unsigned short* Mh   = Xn;   // reuse: Xn dead after QKV
    unsigned short* Hn   = Yb;   // reuse: Yb dead after QKV

    // 1+2. merged preprocessing: LN(X), cast(Y), all transposes, bias concat
    preprocess_kernel<<<NB_LN + NB_CAST + NB_TR + NB_BIAS, 256, 0, stream>>>(
        X, g0, b0, Xn, Y, Yb,
        Wq, Wk, Wv, Wm, W1, W2, WqkvT, WmT, W1T, W2T,
        bq, bk, bv, bqkv);

    // 3. fused QKV projection (768 blocks, 3/CU; 32x32 frags, dbuf BK=32)
    gemm_bt<4, 128><<<dim3(ROWS / 128, 12), 256, 0, stream>>>(
        Xn, Yb, WqkvT, bqkv, nullptr, nullptr, nullptr, nullptr,
        Qb, Kbf, Vtg, ROWS, 3 * DD, DD);

    // 4. attention (512 blocks of 256 threads: b,h,16 q-tiles of 128)
    flash_attn_kernel<<<BB * HH * (NN / 128), 256, 0, stream>>>(Qb, Kbf, Vtg, Mh);

    // 5. head mix + residual (Q) -> Hx fp32   (MT=64 dbuf -> 512 blocks, 2/CU)
    gemm_bt<1, 64><<<dim3(ROWS / 64, DD / 128), 256, 0, stream>>>(
        Mh, nullptr, WmT, bm, Qb, nullptr, nullptr, Hx,
        nullptr, nullptr, nullptr, ROWS, DD, DD);

    // 6. LN(Hx) -> Hn bf16
    ln_kernel<<<ROWS, 256, 0, stream>>>(Hx, g1, b1, Hn);

    // 7. FFN1 + fast gelu -> G bf16  (1024 blocks, 4/CU; 32x32 frags, BK=32)
    gemm_bt<2, 128><<<dim3(ROWS / 128, DFF / 128), 256, 0, stream>>>(
        Hn, nullptr, W1T, bb1, nullptr, nullptr, G, nullptr,
        nullptr, nullptr, nullptr, ROWS, DFF, DD);

    // 8. FFN2 + residual (Hx) -> out fp32  (MT=64 dbuf -> 512 blocks, 2/CU)
    gemm_bt<3, 64><<<dim3(ROWS / 64, DD / 128), 256, 0, stream>>>(
        G, nullptr, W2T, bb2, nullptr, Hx, nullptr, out,
        nullptr, nullptr, nullptr, ROWS, DD, DFF);
}

// Round 13
// 266.578 us; speedup vs baseline: 1.0459x; 1.0200x over previous
//
#include <hip/hip_runtime.h>
#include <cmath>

// ---------------------------------------------------------------------------
// Types / helpers
// ---------------------------------------------------------------------------
typedef __attribute__((ext_vector_type(8))) short bf16x8;   // 8 bf16 = 4 VGPRs
typedef __attribute__((ext_vector_type(4))) float f32x4;
typedef __attribute__((ext_vector_type(16))) float f32x16;  // 32x32 MFMA acc

__device__ __forceinline__ unsigned short f2b(float f) {   // RNE (cold paths)
    union { float f; unsigned u; } c; c.f = f;
    unsigned r = (c.u + 0x7FFFu + ((c.u >> 16) & 1u)) >> 16;
    return (unsigned short)r;
}
// single-instruction 2xf32 -> 2xbf16 pack (RNE); no builtin on gfx950, inline
// asm per guide T12 recipe (HW-verified m214v22).
__device__ __forceinline__ unsigned cvtpk2(float a, float b) {
    unsigned r;
    asm("v_cvt_pk_bf16_f32 %0, %1, %2" : "=v"(r) : "v"(a), "v"(b));
    return r;
}
// scalar f32 -> bf16 in ONE VALU op (low half of cvt_pk; RNE)
__device__ __forceinline__ unsigned short f2b1(float f) {
    return (unsigned short)cvtpk2(f, f);
}
__device__ __forceinline__ float b2f(unsigned short h) {
    union { unsigned u; float f; } c; c.u = ((unsigned)h) << 16;
    return c.f;
}

// async global->LDS 16B (wave-uniform LDS base + lane*16; global src per-lane)
__device__ __forceinline__ void gl2lds16(const unsigned short* g, unsigned short* l) {
    __builtin_amdgcn_global_load_lds(
        (const __attribute__((address_space(1))) unsigned int*)(g),
        (__attribute__((address_space(3))) unsigned int*)(l),
        16, 0, 0);
}

// Problem constants
#define BB   4
#define NN   2048
#define DD   512
#define HH   8
#define DH   64
#define DFF  2048
#define ROWS (BB * NN)          // 8192
#define SCALE_QK 0.044194173824159216f   // 1/sqrt(512)
// 1/sqrt(512) * log2(e): exp(S) == exp2(S') with S' from pre-scaled Q
#define SCALE_QK_E2 0.06376112595042793f
// gelu-tanh: 0.5v(1+tanh(u)) == v/(1+exp2(-u2)), u2 = v*(GA + GB*v^2)
// GA = 2*log2(e)*0.7978845608, GB = GA*0.044715
#define GELU_A 2.3022082f
#define GELU_B 0.10294324f

// ---------------------------------------------------------------------------
// LayerNorm row body (fp32 in -> bf16 out), 256 threads per 512-row.
// ---------------------------------------------------------------------------
__device__ __forceinline__ void ln_row_body(const float* __restrict__ X,
                                            const float* __restrict__ g,
                                            const float* __restrict__ be,
                                            unsigned short* __restrict__ out,
                                            int row, int tid, float* sred)
{
    const float* x = X + (size_t)row * DD;
    float x0 = x[tid], x1 = x[tid + 256];
    float s = x0 + x1, sq = x0 * x0 + x1 * x1;
#pragma unroll
    for (int off = 32; off; off >>= 1) {
        s  += __shfl_down(s,  off);
        sq += __shfl_down(sq, off);
    }
    const int wid = tid >> 6;
    if ((tid & 63) == 0) { sred[wid] = s; sred[4 + wid] = sq; }
    __syncthreads();
    float ts = 0.f, tq = 0.f;
#pragma unroll
    for (int i = 0; i < 4; ++i) { ts += sred[i]; tq += sred[4 + i]; }
    const float mean = ts * (1.0f / DD);
    const float var  = tq * (1.0f / DD) - mean * mean;
    const float rinv = rsqrtf(var + 1e-5f);
    unsigned short* o = out + (size_t)row * DD;
    o[tid]       = f2b((x0 - mean) * rinv * g[tid]       + be[tid]);
    o[tid + 256] = f2b((x1 - mean) * rinv * g[tid + 256] + be[tid + 256]);
}

__global__ __launch_bounds__(256)
void ln_kernel(const float* __restrict__ X, const float* __restrict__ g,
               const float* __restrict__ be, unsigned short* __restrict__ out)
{
    __shared__ float sred[8];
    ln_row_body(X, g, be, out, blockIdx.x, threadIdx.x, sred);
}

// ---------------------------------------------------------------------------
// MERGED preprocessing (one launch instead of 4): block-range dispatch.
//   [0, 8192)            : LN(X) -> Xn bf16
//   [8192, 10240)        : cast Y -> Yb bf16 (4 elems/thread)
//   [10240, 13312)       : all weight transposes (3072 32x32 tiles)
//   [13312, 13318)       : bias concat bq|bk|bv -> bqkv
// ---------------------------------------------------------------------------
#define NB_LN   ROWS
#define NB_CAST (ROWS * DD / 4 / 256)
#define NB_TR   3072
#define NB_BIAS 6

__global__ __launch_bounds__(256)
void preprocess_kernel(const float* __restrict__ X, const float* __restrict__ g0,
                       const float* __restrict__ b0, unsigned short* __restrict__ Xn,
                       const float* __restrict__ Y, unsigned short* __restrict__ Yb,
                       const float* __restrict__ Wq, const float* __restrict__ Wk,
                       const float* __restrict__ Wv, const float* __restrict__ Wm,
                       const float* __restrict__ W1, const float* __restrict__ W2,
                       unsigned short* __restrict__ WqkvT, unsigned short* __restrict__ WmT,
                       unsigned short* __restrict__ W1T, unsigned short* __restrict__ W2T,
                       const float* __restrict__ bq, const float* __restrict__ bk,
                       const float* __restrict__ bv, float* __restrict__ bqkv)
{
    __shared__ float smem[32 * 33];
    const int blk = blockIdx.x;
    const int tid = threadIdx.x;

    if (blk < NB_LN) {
        ln_row_body(X, g0, b0, Xn, blk, tid, smem);
    } else if (blk < NB_LN + NB_CAST) {
        int i = (blk - NB_LN) * 256 + tid;
        float4 v = ((const float4*)Y)[i];
        ushort4 o;
        o.x = f2b(v.x); o.y = f2b(v.y); o.z = f2b(v.z); o.w = f2b(v.w);
        ((ushort4*)Yb)[i] = o;
    } else if (blk < NB_LN + NB_CAST + NB_TR) {
        const int t = blk - (NB_LN + NB_CAST);
        float (*tile)[33] = (float(*)[33])smem;
        const float* W; unsigned short* Wt; int K, Nn, n0, k0;
        if (t < 1024) {
            W = W1; Wt = W1T; K = DD; Nn = DFF;
            n0 = (t & 63) * 32; k0 = (t >> 6) * 32;
        } else if (t < 2048) {
            int u = t - 1024;
            W = W2; Wt = W2T; K = DFF; Nn = DD;
            n0 = (u & 15) * 32; k0 = (u >> 4) * 32;
        } else {
            int u = t - 2048;
            int m = u >> 8;            // 0..3 : Wq,Wk,Wv,Wm
            int v = u & 255;
            K = DD; Nn = DD;
            n0 = (v & 15) * 32; k0 = (v >> 4) * 32;
            if (m == 0)      { W = Wq; Wt = WqkvT; }
            else if (m == 1) { W = Wk; Wt = WqkvT + (size_t)DD * DD; }
            else if (m == 2) { W = Wv; Wt = WqkvT + (size_t)2 * DD * DD; }
            else             { W = Wm; Wt = WmT; }
        }
        const int tx = tid & 31, ty = tid >> 5;  // ty 0..7
#pragma unroll
        for (int i = 0; i < 4; ++i)
            tile[ty + i * 8][tx] = W[(size_t)(k0 + ty + i * 8) * Nn + n0 + tx];
        __syncthreads();
#pragma unroll
        for (int i = 0; i < 4; ++i)
            Wt[(size_t)(n0 + ty + i * 8) * K + k0 + tx] = f2b(tile[tx][ty + i * 8]);
    } else {
        int i = (blk - (NB_LN + NB_CAST + NB_TR)) * 256 + tid;   // 0..1535
        float v = (i < 512) ? bq[i] : (i < 1024) ? bk[i - 512] : bv[i - 1024];
        bqkv[i] = v;
    }
}

// ---------------------------------------------------------------------------
// GEMM: C[M,N] = A[M,K] @ Bt[N,K]^T + bias, bf16 in, fp32 accumulate.
// 256 threads (4 waves), double-buffered counted-vmcnt pipeline, with
// s_setprio(1) around the MFMA clusters (T5; isolated -2.2us in r10).
// MT=128: 32x32x16 MFMAs, BK=32, XOR-swizzled [128][32] LDS (both sides).
// MT=64 : 16x16x32 MFMAs, BK=64 (original fragment path).
// r13: epilogue VALU polish -- single-op cvt_pk bf16 stores (Q/K/V, gelu)
// and gelu rewritten as v*sigmoid(2u) = v/(1+exp2(-u2)) (~6 ops vs ~14).
// MODE 1: += bf16 residual (resB), store fp32 (outF)            [mix]
// MODE 2: sigmoid-form gelu, store bf16 (outB)                  [FFN1]
// MODE 3: += fp32 residual (resF), store fp32 (outF)            [FFN2]
// MODE 4: fused QKV, N=1536 (MT=128): col<512->Qb, <1024->Kbf, else V
//         transposed into Vtg[b*512+feat][token]; A=(by<4)?A0:A1.
// ---------------------------------------------------------------------------
template <int MODE, int MT>
__global__ __launch_bounds__(256, (MT == 128) ? 4 : 2)
void gemm_bt(const unsigned short* __restrict__ A0, const unsigned short* __restrict__ A1,
             const unsigned short* __restrict__ Bt,
             const float* __restrict__ bias,
             const unsigned short* __restrict__ resB, const float* __restrict__ resF,
             unsigned short* __restrict__ outB, float* __restrict__ outF,
             unsigned short* __restrict__ outQ, unsigned short* __restrict__ outK,
             unsigned short* __restrict__ outVt,
             int M, int N, int K)
{
    const int tid  = threadIdx.x;
    const int wave = tid >> 6, lane = tid & 63;
    const int m0 = blockIdx.x * MT, n0 = blockIdx.y * 128;
    const unsigned short* A = (MODE == 4 && blockIdx.y >= 4) ? A1 : A0;

    if constexpr (MT == 128) {
        // ================= 32x32x16 fragment path =================
        __shared__ __align__(16) unsigned short As[2][128 * 32];
        __shared__ __align__(16) unsigned short Bs[2][128 * 32];
        const int l31 = lane & 31, hi5 = lane >> 5, l3 = lane & 3;
        const int wm = (wave & 1) * 64, wn = (wave >> 1) * 64;

        const int srow4 = lane >> 2;
        const int scsw  = ((lane & 3) ^ (srow4 & 3)) * 8;
        const unsigned short* gA = A  + (size_t)(m0 + wave * 32 + srow4) * K + scsw;
        const unsigned short* gB = Bt + (size_t)(n0 + wave * 32 + srow4) * K + scsw;

        f32x16 acc[2][2];
#pragma unroll
        for (int fi = 0; fi < 2; ++fi)
#pragma unroll
            for (int fj = 0; fj < 2; ++fj)
#pragma unroll
                for (int r = 0; r < 16; ++r) acc[fi][fj][r] = 0.f;

        auto stage = [&](int kk, int buf) {
#pragma unroll
            for (int c = 0; c < 2; ++c) {
                gl2lds16(gA + (size_t)c * 16 * K + kk, &As[buf][(wave * 32 + c * 16) * 32]);
                gl2lds16(gB + (size_t)c * 16 * K + kk, &Bs[buf][(wave * 32 + c * 16) * 32]);
            }
        };
        auto compute = [&](int buf) {
#pragma unroll
            for (int h = 0; h < 2; ++h) {
                const int cs = (((h << 1) + hi5) ^ l3) * 8;   // swizzled chunk
                bf16x8 a[2], b[2];
#pragma unroll
                for (int f = 0; f < 2; ++f) {
                    a[f] = *(const bf16x8*)&As[buf][(wm + f * 32 + l31) * 32 + cs];
                    b[f] = *(const bf16x8*)&Bs[buf][(wn + f * 32 + l31) * 32 + cs];
                }
                __builtin_amdgcn_s_setprio(1);
#pragma unroll
                for (int fi = 0; fi < 2; ++fi)
#pragma unroll
                    for (int fj = 0; fj < 2; ++fj)
                        acc[fi][fj] = __builtin_amdgcn_mfma_f32_32x32x16_bf16(
                            a[fi], b[fj], acc[fi][fj], 0, 0, 0);
                __builtin_amdgcn_s_setprio(0);
            }
        };

        stage(0, 0);
        const int NK = K / 32;
        for (int kt = 0; kt < NK; ++kt) {
            const int cur = kt & 1;
            if (kt + 1 < NK) {
                stage((kt + 1) * 32, cur ^ 1);
                asm volatile("s_waitcnt vmcnt(4)" ::: "memory");
            } else {
                asm volatile("s_waitcnt vmcnt(0)" ::: "memory");
            }
            __builtin_amdgcn_sched_barrier(0);
            __builtin_amdgcn_s_barrier();
            __builtin_amdgcn_sched_barrier(0);
            compute(cur);
            asm volatile("s_waitcnt lgkmcnt(0)" ::: "memory");
            __builtin_amdgcn_sched_barrier(0);
            __builtin_amdgcn_s_barrier();
            __builtin_amdgcn_sched_barrier(0);
        }

        // Epilogue. C/D: col = l31, row = (reg&3) + 8*(reg>>2) + 4*hi5.
#pragma unroll
        for (int fi = 0; fi < 2; ++fi) {
#pragma unroll
            for (int fj = 0; fj < 2; ++fj) {
                const int col = n0 + wn + fj * 32 + l31;
                const float bsv = bias[col];
#pragma unroll
                for (int g = 0; g < 4; ++g) {
                    const int row0 = m0 + wm + fi * 32 + 8 * g + 4 * hi5;
                    if (MODE == 4) {
                        if (col < DD) {
#pragma unroll
                            for (int rr = 0; rr < 4; ++rr)
                                outQ[(size_t)(row0 + rr) * DD + col] =
                                    f2b1(acc[fi][fj][4 * g + rr] + bsv);
                        } else if (col < 2 * DD) {
#pragma unroll
                            for (int rr = 0; rr < 4; ++rr)
                                outK[(size_t)(row0 + rr) * DD + (col - DD)] =
                                    f2b1(acc[fi][fj][4 * g + rr] + bsv);
                        } else {
                            const int feat = col - 2 * DD;
                            const int bb = row0 >> 11;
                            const int n  = row0 & (NN - 1);
                            uint2 o;   // 2x cvt_pk replaces 4 scalar packs
                            o.x = cvtpk2(acc[fi][fj][4 * g + 0] + bsv,
                                         acc[fi][fj][4 * g + 1] + bsv);
                            o.y = cvtpk2(acc[fi][fj][4 * g + 2] + bsv,
                                         acc[fi][fj][4 * g + 3] + bsv);
                            *(uint2*)&outVt[((size_t)bb * DD + feat) * NN + n] = o;
                        }
                    } else {   // MODE 2: gelu = v/(1+exp2(-u2)), bf16 store
#pragma unroll
                        for (int rr = 0; rr < 4; ++rr) {
                            float v  = acc[fi][fj][4 * g + rr] + bsv;
                            float u2 = v * (GELU_A + GELU_B * v * v);
                            float em = __builtin_amdgcn_exp2f(-u2);
                            float gl = v * __builtin_amdgcn_rcpf(1.0f + em);
                            outB[(size_t)(row0 + rr) * N + col] = f2b1(gl);
                        }
                    }
                }
            }
        }
    } else {
        // ================= 16x16x32 fragment path (MT=64) =================
        __shared__ __align__(16) unsigned short As[2][2][MT * 32];
        __shared__ __align__(16) unsigned short Bs[2][2][128 * 32];
        const int quad = lane >> 4, l16 = lane & 15;
        const int MI  = MT / 32;               // 2 accumulator row-tiles
        const int RPW = MT / 4;                // A rows staged per wave
        const int wm = (wave & 1) * (MT / 2), wn = (wave >> 1) * 64;

        const int srow = lane >> 2;
        const int sc8  = (lane & 3) * 8;
        const unsigned short* gA = A  + (size_t)(m0 + wave * RPW + srow) * K + sc8;
        const unsigned short* gB = Bt + (size_t)(n0 + wave * 32  + srow) * K + sc8;

        f32x4 acc[MI][4];
#pragma unroll
        for (int i = 0; i < MI; ++i)
#pragma unroll
            for (int j = 0; j < 4; ++j)
                acc[i][j] = (f32x4){0.f, 0.f, 0.f, 0.f};

        auto stage = [&](int kk, int buf) {
#pragma unroll
            for (int ih = 0; ih < RPW / 16; ++ih)
#pragma unroll
                for (int half = 0; half < 2; ++half)
                    gl2lds16(gA + (size_t)ih * 16 * K + half * 32 + kk,
                             &As[buf][half][(wave * RPW + ih * 16) * 32]);
#pragma unroll
            for (int ih = 0; ih < 2; ++ih)
#pragma unroll
                for (int half = 0; half < 2; ++half)
                    gl2lds16(gB + (size_t)ih * 16 * K + half * 32 + kk,
                             &Bs[buf][half][(wave * 32 + ih * 16) * 32]);
        };
        auto compute = [&](int buf) {
#pragma unroll
            for (int h = 0; h < 2; ++h) {
                bf16x8 a[MI], b[4];
#pragma unroll
                for (int i = 0; i < MI; ++i)
                    a[i] = *(const bf16x8*)&As[buf][h][(wm + i * 16 + l16) * 32 + quad * 8];
#pragma unroll
                for (int j = 0; j < 4; ++j)
                    b[j] = *(const bf16x8*)&Bs[buf][h][(wn + j * 16 + l16) * 32 + quad * 8];
                __builtin_amdgcn_s_setprio(1);
#pragma unroll
                for (int i = 0; i < MI; ++i)
#pragma unroll
                    for (int j = 0; j < 4; ++j)
                        acc[i][j] = __builtin_amdgcn_mfma_f32_16x16x32_bf16(a[i], b[j], acc[i][j], 0, 0, 0);
                __builtin_amdgcn_s_setprio(0);
            }
        };

        stage(0, 0);
        const int NK = K / 64;
        for (int kt = 0; kt < NK; ++kt) {
            const int cur = kt & 1;
            if (kt + 1 < NK) {
                stage((kt + 1) * 64, cur ^ 1);
                asm volatile("s_waitcnt vmcnt(6)" ::: "memory");
            } else {
                asm volatile("s_waitcnt vmcnt(0)" ::: "memory");
            }
            __builtin_amdgcn_sched_barrier(0);
            __builtin_amdgcn_s_barrier();
            __builtin_amdgcn_sched_barrier(0);
            compute(cur);
            asm volatile("s_waitcnt lgkmcnt(0)" ::: "memory");
            __builtin_amdgcn_sched_barrier(0);
            __builtin_amdgcn_s_barrier();
            __builtin_amdgcn_sched_barrier(0);
        }

        // Epilogue. C/D layout: col = lane&15, row = quad*4 + reg.
#pragma unroll
        for (int i = 0; i < MI; ++i) {
#pragma unroll
            for (int j = 0; j < 4; ++j) {
                const int col  = n0 + wn + j * 16 + l16;
                const int row0 = m0 + wm + i * 16 + quad * 4;
                const float bsv = bias[col];
#pragma unroll
                for (int r = 0; r < 4; ++r) {
                    const size_t idx = (size_t)(row0 + r) * N + col;
                    float v = acc[i][j][r] + bsv;
                    if (MODE == 1) {
                        outF[idx] = v + b2f(resB[idx]);
                    } else {   // MODE 3
                        outF[idx] = v + resF[idx];
                    }
                }
            }
        }
    }
}

// ---------------------------------------------------------------------------
// Flash attention v15 (session-best attn, 53.1us measured r12): block =
// (b, h, 128-q tile), 256 THREADS / 4 WAVES, grid 512, 32 q per wave.
//  * dbuf LDS K/V via global_load_lds, counted vmcnt(4), raw barriers
//  * linear [64][64] LDS + XOR swizzle via pre-swizzled global source
//  * XCD swizzle, exp2 pre-scale fold, PLD=36, setprio on MFMA clusters
//  * v_cvt_pk_bf16_f32 single-op packs on the softmax path
// ---------------------------------------------------------------------------
#define PLD 36   // Pt row stride in dwords (144B, 16B-aligned)

__global__ __launch_bounds__(256, 2)
void flash_attn_kernel(const unsigned short* __restrict__ Q,
                       const unsigned short* __restrict__ Kb,
                       const unsigned short* __restrict__ Vtg,
                       unsigned short* __restrict__ O)
{
    __shared__ __align__(16) unsigned short Ks[2][64 * 64];    // 2 x 8192 B
    __shared__ __align__(16) unsigned short Vt[2][64 * 64];    // 2 x 8192 B
    __shared__ __align__(16) unsigned int   Pt[4 * 32 * PLD];  // 18432 B

    const int tid  = threadIdx.x;
    const int wave = tid >> 6, lane = tid & 63;
    const int quad = lane >> 4, l16 = lane & 15;
    const int lsw  = l16 & 7;              // read-side XOR key (= row&7)

    // XCD swizzle: 512 blocks on 8 XCDs -> XCD x gets work-ids [x*64,(x+1)*64)
    // = 4 consecutive (b,h) panels; their K/V stays resident in that L2.
    const int bid = (blockIdx.x & 7) * 64 + (blockIdx.x >> 3);
    const int qt = bid & 15;          // 16 q-tiles of 128
    const int bh = bid >> 4;
    const int b  = bh >> 3;
    const int h  = bh & 7;
    const size_t rowbase = (size_t)b * NN * DD;
    const int q0 = qt * 128 + wave * 32;   // this wave's q base (32 q)
    const int hc = h * DH;
    unsigned int* myPt = &Pt[wave * 32 * PLD];

    // staging geometry: each wave stages 16 rows of K and 16 rows (features)
    // of V per tile via 2+2 gl2lds16 calls.  Lane's linear LDS slot within a
    // call: row_local = lane>>3, chunk = lane&7.  Global source column is
    // pre-swizzled: srcChunk = (lane&7) ^ (lane>>3)  (= chunk ^ (row&7)).
    const int srow8 = lane >> 3;                       // 0..7
    const int ssw   = ((lane & 7) ^ srow8) * 8;        // elements
    const unsigned short* gKs = Kb  + rowbase + hc;
    const unsigned short* gVs = Vtg + ((size_t)b * DD + hc) * NN;

    // prologue: stage tile 0 into buffer 0 (async)
#pragma unroll
    for (int c = 0; c < 2; ++c) {
        gl2lds16(gKs + (size_t)(wave * 16 + c * 8 + srow8) * DD + ssw,
                 &Ks[0][(wave * 2 + c) * 512]);
        gl2lds16(gVs + (size_t)(wave * 16 + c * 8 + srow8) * NN + ssw,
                 &Vt[0][(wave * 2 + c) * 512]);
    }

    // hoist Q B-frags, pre-scaled by log2(e)/sqrt(512):
    // q = q0 + t*16 + l16, dh = hh*32 + quad*8
    bf16x8 Qf[2][2];
#pragma unroll
    for (int t = 0; t < 2; ++t)
#pragma unroll
        for (int hh = 0; hh < 2; ++hh) {
            union { bf16x8 v; unsigned short s[8]; unsigned u[4]; } raw, sc;
            raw.v = *(const bf16x8*)&Q[rowbase + (size_t)(q0 + t * 16 + l16) * DD
                                        + hc + hh * 32 + quad * 8];
#pragma unroll
            for (int p = 0; p < 4; ++p)
                sc.u[p] = cvtpk2(b2f(raw.s[2 * p]) * SCALE_QK_E2,
                                 b2f(raw.s[2 * p + 1]) * SCALE_QK_E2);
            Qf[t][hh] = sc.v;
        }

    f32x4 Oacc[2][4];   // [q-subtile][dh-tile]: O^T, col=q(l16), row=dh=16t2+4quad+r
#pragma unroll
    for (int t = 0; t < 2; ++t)
#pragma unroll
        for (int t2 = 0; t2 < 4; ++t2) Oacc[t][t2] = (f32x4){0.f, 0.f, 0.f, 0.f};
    float lsum[2] = {0.f, 0.f};

    const int NT = NN / 64;
    for (int kt = 0; kt < NT; ++kt) {
        const int cur = kt & 1;
        // issue NEXT tile's staging into the other buffer, then wait only for
        // the CURRENT tile's 4 calls (issued one compute-phase ago).
        if (kt + 1 < NT) {
            const int nv0 = (kt + 1) * 64;
            const int nb = cur ^ 1;
#pragma unroll
            for (int c = 0; c < 2; ++c) {
                gl2lds16(gKs + (size_t)(nv0 + wave * 16 + c * 8 + srow8) * DD + ssw,
                         &Ks[nb][(wave * 2 + c) * 512]);
                gl2lds16(gVs + (size_t)(wave * 16 + c * 8 + srow8) * NN + nv0 + ssw,
                         &Vt[nb][(wave * 2 + c) * 512]);
            }
            asm volatile("s_waitcnt vmcnt(4)" ::: "memory");
        } else {
            asm volatile("s_waitcnt vmcnt(0)" ::: "memory");
        }
        __builtin_amdgcn_sched_barrier(0);
        __builtin_amdgcn_s_barrier();
        __builtin_amdgcn_sched_barrier(0);

        // ---- S^T: St[t][j] (16 kv x 16 q); each kf feeds 2 MFMAs ----
        __builtin_amdgcn_s_setprio(1);
        f32x4 St[2][4];
#pragma unroll
        for (int t = 0; t < 2; ++t)
#pragma unroll
            for (int j = 0; j < 4; ++j) St[t][j] = (f32x4){0.f, 0.f, 0.f, 0.f};
#pragma unroll
        for (int j = 0; j < 4; ++j) {
#pragma unroll
            for (int hh = 0; hh < 2; ++hh) {
                bf16x8 kf = *(const bf16x8*)&Ks[cur][(j * 16 + l16) * 64
                                                     + (((hh << 2) + quad) ^ lsw) * 8];
#pragma unroll
                for (int t = 0; t < 2; ++t)
                    St[t][j] = __builtin_amdgcn_mfma_f32_16x16x32_bf16(kf, Qf[t][hh], St[t][j], 0, 0, 0);
            }
        }
        __builtin_amdgcn_s_setprio(0);

        // ---- exp2 (scale+log2e pre-folded into Q), scalar lsum,
        //      pack P^T via single-instr v_cvt_pk_bf16_f32 ----
#pragma unroll
        for (int t = 0; t < 2; ++t) {
            unsigned int* rowp = &myPt[(t * 16 + l16) * PLD];
#pragma unroll
            for (int j = 0; j < 4; ++j) {
                float p0 = __builtin_amdgcn_exp2f(St[t][j][0]);
                float p1 = __builtin_amdgcn_exp2f(St[t][j][1]);
                float p2 = __builtin_amdgcn_exp2f(St[t][j][2]);
                float p3 = __builtin_amdgcn_exp2f(St[t][j][3]);
                lsum[t] += (p0 + p1) + (p2 + p3);
                uint2 w; w.x = cvtpk2(p0, p1); w.y = cvtpk2(p2, p3);
                *(uint2*)&rowp[j * 8 + quad * 2] = w;
            }
        }

        // ---- O^T += V^T . P^T : each vf feeds 2 MFMAs ----
        __builtin_amdgcn_s_setprio(1);
#pragma unroll
        for (int ks = 0; ks < 2; ++ks) {
            bf16x8 pf[2];
#pragma unroll
            for (int t = 0; t < 2; ++t)
                pf[t] = *(const bf16x8*)&myPt[(t * 16 + l16) * PLD + ks * 16 + quad * 4];
#pragma unroll
            for (int t2 = 0; t2 < 4; ++t2) {
                bf16x8 vf = *(const bf16x8*)&Vt[cur][(t2 * 16 + l16) * 64
                                                     + (((ks << 2) + quad) ^ lsw) * 8];
#pragma unroll
                for (int t = 0; t < 2; ++t)
                    Oacc[t][t2] = __builtin_amdgcn_mfma_f32_16x16x32_bf16(vf, pf[t], Oacc[t][t2], 0, 0, 0);
            }
        }
        __builtin_amdgcn_s_setprio(0);

        // all waves done reading buf[cur] before next iter stages into it
        asm volatile("s_waitcnt lgkmcnt(0)" ::: "memory");
        __builtin_amdgcn_sched_barrier(0);
        __builtin_amdgcn_s_barrier();
        __builtin_amdgcn_sched_barrier(0);
    }

    // reduce lsum across the 4 quads (same q = l16)
#pragma unroll
    for (int t = 0; t < 2; ++t) {
        lsum[t] += __shfl_xor(lsum[t], 16);
        lsum[t] += __shfl_xor(lsum[t], 32);
    }
    const float rl0 = 1.0f / lsum[0], rl1 = 1.0f / lsum[1];

    // transpose O^T -> O via wave-private LDS (reuse Pt), coalesced store
#pragma unroll
    for (int t = 0; t < 2; ++t) {
        const float rl = t ? rl1 : rl0;
        unsigned int* rowp = &myPt[(t * 16 + l16) * PLD];
#pragma unroll
        for (int t2 = 0; t2 < 4; ++t2) {
            uint2 w;
            w.x = cvtpk2(Oacc[t][t2][0] * rl, Oacc[t][t2][1] * rl);
            w.y = cvtpk2(Oacc[t][t2][2] * rl, Oacc[t][t2][3] * rl);
            *(uint2*)&rowp[t2 * 8 + quad * 2] = w;
        }
    }
#pragma unroll
    for (int ii = 0; ii < 4; ++ii) {
        int flat  = lane + ii * 64;       // 0..255 within wave
        int row   = flat >> 3;            // q within wave (0..31)
        int chunk = flat & 7;
        uint4 v = *(const uint4*)&myPt[row * PLD + chunk * 4];
        *(uint4*)&O[rowbase + (size_t)(q0 + row) * DD + hc + chunk * 8] = v;
    }
}

// ---------------------------------------------------------------------------
// Launch
// ---------------------------------------------------------------------------
extern "C" void kernel_launch(void* const* d_in, const int* in_sizes, int n_in,
                              void* d_out, int out_size, void* d_ws, size_t ws_size,
                              hipStream_t stream)
{
    (void)in_sizes; (void)n_in; (void)out_size; (void)ws_size;

    const float* X   = (const float*)d_in[0];
    const float* Y   = (const float*)d_in[1];
    const float* Wq  = (const float*)d_in[2];
    const float* bq  = (const float*)d_in[3];
    const float* Wk  = (const float*)d_in[4];
    const float* bk  = (const float*)d_in[5];
    const float* Wv  = (const float*)d_in[6];
    const float* bv  = (const float*)d_in[7];
    const float* Wm  = (const float*)d_in[8];
    const float* bm  = (const float*)d_in[9];
    const float* g0  = (const float*)d_in[10];
    const float* b0  = (const float*)d_in[11];
    const float* g1  = (const float*)d_in[12];
    const float* b1  = (const float*)d_in[13];
    const float* W1  = (const float*)d_in[14];
    const float* bb1 = (const float*)d_in[15];
    const float* W2  = (const float*)d_in[16];
    const float* bb2 = (const float*)d_in[17];
    float* out = (float*)d_out;

    // workspace carve-up
    char* ws = (char*)d_ws;
    size_t off = 0;
    auto carve = [&](size_t bytes) { void* p = ws + off; off += bytes; return p; };
    const size_t BND2 = (size_t)ROWS * DD * 2;       // 8 MB bf16 [8192,512]

    unsigned short* Xn   = (unsigned short*)carve(BND2);
    unsigned short* Yb   = (unsigned short*)carve(BND2);
    unsigned short* WqkvT= (unsigned short*)carve((size_t)3 * DD * DD * 2);
    unsigned short* WmT  = (unsigned short*)carve((size_t)DD * DD * 2);
    unsigned short* W1T  = (unsigned short*)carve((size_t)DD * DFF * 2);
    unsigned short* W2T  = (unsigned short*)carve((size_t)DFF * DD * 2);
    float*          bqkv = (float*)carve(1536 * 4);
    unsigned short* Qb   = (unsigned short*)carve(BND2);
    unsigned short* Kbf  = (unsigned short*)carve(BND2);
    unsigned short* Vtg  = (unsigned short*)carve(BND2);  // V^T [b*512+feat][token]
    float*          Hx   = (float*)carve((size_t)ROWS * DD * 4);
    unsigned short* G    = (unsigned short*)carve((size_t)ROWS * DFF * 2);
    unsigned short* Mh   = Xn;   // reuse: Xn dead after QKV
    unsigned short* Hn   = Yb;   // reuse: Yb dead after QKV

    // 1+2. merged preprocessing: LN(X), cast(Y), all transposes, bias concat
    preprocess_kernel<<<NB_LN + NB_CAST + NB_TR + NB_BIAS, 256, 0, stream>>>(
        X, g0, b0, Xn, Y, Yb,
        Wq, Wk, Wv, Wm, W1, W2, WqkvT, WmT, W1T, W2T,
        bq, bk, bv, bqkv);

    // 3. fused QKV projection (768 blocks, 3/CU; 32x32 frags, dbuf BK=32)
    gemm_bt<4, 128><<<dim3(ROWS / 128, 12), 256, 0, stream>>>(
        Xn, Yb, WqkvT, bqkv, nullptr, nullptr, nullptr, nullptr,
        Qb, Kbf, Vtg, ROWS, 3 * DD, DD);

    // 4. attention (512 blocks of 256 threads: b,h,16 q-tiles of 128)
    flash_attn_kernel<<<BB * HH * (NN / 128), 256, 0, stream>>>(Qb, Kbf, Vtg, Mh);

    // 5. head mix + residual (Q) -> Hx fp32   (MT=64 dbuf -> 512 blocks, 2/CU)
    gemm_bt<1, 64><<<dim3(ROWS / 64, DD / 128), 256, 0, stream>>>(
        Mh, nullptr, WmT, bm, Qb, nullptr, nullptr, Hx,
        nullptr, nullptr, nullptr, ROWS, DD, DD);

    // 6. LN(Hx) -> Hn bf16
    ln_kernel<<<ROWS, 256, 0, stream>>>(Hx, g1, b1, Hn);

    // 7. FFN1 + sigmoid-form gelu -> G bf16 (1024 blocks, 4/CU; 32x32, BK=32)
    gemm_bt<2, 128><<<dim3(ROWS / 128, DFF / 128), 256, 0, stream>>>(
        Hn, nullptr, W1T, bb1, nullptr, nullptr, G, nullptr,
        nullptr, nullptr, nullptr, ROWS, DFF, DD);

    // 8. FFN2 + residual (Hx) -> out fp32  (MT=64 dbuf -> 512 blocks, 2/CU)
    gemm_bt<3, 64><<<dim3(ROWS / 64, DD / 128), 256, 0, stream>>>(
        G, nullptr, W2T, bb2, nullptr, Hx, nullptr, out,
        nullptr, nullptr, nullptr, ROWS, DD, DFF);
}